// Round 1
// baseline (4359.473 us; speedup 1.0000x reference)
//
#include <hip/hip_runtime.h>
#include <hip/hip_bf16.h>

#define N_NODES 100000
#define N_EDGES 200000
#define N_GRAPHS 4096
#define NODE_DIM 64
#define HID 256
#define N_GAT 4
#define NEG_SLOPE 0.2f
#define EPS 1e-9f

__device__ __forceinline__ unsigned f2u(float f) {
    unsigned u = __float_as_uint(f);
    return (u & 0x80000000u) ? ~u : (u | 0x80000000u);
}
__device__ __forceinline__ float u2f(unsigned u) {
    return (u & 0x80000000u) ? __uint_as_float(u & 0x7fffffffu)
                             : __uint_as_float(~u);
}

// h = node_feats @ w_embed + b_embed   [N, 64] @ [64, 256]
__global__ void embed_kernel(const float* __restrict__ nf,
                             const float* __restrict__ W,
                             const float* __restrict__ b,
                             float* __restrict__ h) {
    int n = blockIdx.x, t = threadIdx.x;
    __shared__ float x[NODE_DIM];
    if (t < NODE_DIM) x[t] = nf[n * NODE_DIM + t];
    __syncthreads();
    float acc = b[t];
#pragma unroll
    for (int k = 0; k < NODE_DIM; ++k) acc += x[k] * W[k * HID + t];
    h[n * HID + t] = acc;
}

// z = h @ W ; el = z @ al ; er = z @ ar   (per node, 256 threads)
__global__ void node_linear(const float* __restrict__ h,
                            const float* __restrict__ W,
                            const float* __restrict__ al,
                            const float* __restrict__ ar,
                            float* __restrict__ z,
                            float* __restrict__ el,
                            float* __restrict__ er) {
    int n = blockIdx.x, t = threadIdx.x;
    __shared__ float x[HID];
    x[t] = h[n * HID + t];
    __syncthreads();
    float acc = 0.f;
#pragma unroll 8
    for (int k = 0; k < HID; ++k) acc += x[k] * W[k * HID + t];
    z[n * HID + t] = acc;

    float pl = acc * al[t];
    float pr = acc * ar[t];
#pragma unroll
    for (int off = 32; off > 0; off >>= 1) {
        pl += __shfl_down(pl, off);
        pr += __shfl_down(pr, off);
    }
    __shared__ float sl[4], sr[4];
    int w = t >> 6, lane = t & 63;
    if (lane == 0) { sl[w] = pl; sr[w] = pr; }
    __syncthreads();
    if (t == 0) {
        el[n] = sl[0] + sl[1] + sl[2] + sl[3];
        er[n] = sr[0] + sr[1] + sr[2] + sr[3];
    }
}

// e = leaky_relu(el[src] + er[dst]); segment max into emax_u (monotone-uint)
__global__ void edge_max(const int* __restrict__ src, const int* __restrict__ dst,
                         const float* __restrict__ el, const float* __restrict__ er,
                         float* __restrict__ e, unsigned* __restrict__ emax_u) {
    int i = blockIdx.x * blockDim.x + threadIdx.x;
    if (i >= N_EDGES) return;
    float v = el[src[i]] + er[dst[i]];
    v = (v >= 0.f) ? v : NEG_SLOPE * v;
    e[i] = v;
    atomicMax(&emax_u[dst[i]], f2u(v));
}

// ex = exp(e - emax[dst]); esum[dst] += ex
__global__ void edge_exp(const int* __restrict__ dst,
                         const float* __restrict__ e,
                         const unsigned* __restrict__ emax_u,
                         float* __restrict__ ex, float* __restrict__ esum) {
    int i = blockIdx.x * blockDim.x + threadIdx.x;
    if (i >= N_EDGES) return;
    int d = dst[i];
    float v = expf(e[i] - u2f(emax_u[d]));
    ex[i] = v;
    atomicAdd(&esum[d], v);
}

// accA[dst,:] += (ex/(esum[dst]+eps)) * z[src,:]   (accA pre-holds h -> residual)
__global__ void edge_scatter(const int* __restrict__ src, const int* __restrict__ dst,
                             const float* __restrict__ ex, const float* __restrict__ esum,
                             const float* __restrict__ z, float* __restrict__ accA) {
    int e = blockIdx.x, t = threadIdx.x;
    int s = src[e], d = dst[e];
    float alpha = ex[e] / (esum[d] + EPS);
    atomicAdd(&accA[d * HID + t], alpha * z[s * HID + t]);
}

__global__ void relu4_kernel(float4* __restrict__ A, int n4) {
    int i = blockIdx.x * blockDim.x + threadIdx.x;
    if (i >= n4) return;
    float4 v = A[i];
    v.x = fmaxf(v.x, 0.f); v.y = fmaxf(v.y, 0.f);
    v.z = fmaxf(v.z, 0.f); v.w = fmaxf(v.w, 0.f);
    A[i] = v;
}

// g[graph_ids[n], :] += h[n, :]
__global__ void pool_kernel(const float* __restrict__ h,
                            const int* __restrict__ gid,
                            float* __restrict__ g) {
    int n = blockIdx.x, t = threadIdx.x;
    atomicAdd(&g[gid[n] * HID + t], h[n * HID + t]);
}

// fused MLP: relu(g@w1+b1) -> relu(@w2+b2) -> @w3+b3
__global__ void mlp_kernel(const float* __restrict__ g,
                           const float* __restrict__ w1, const float* __restrict__ b1,
                           const float* __restrict__ w2, const float* __restrict__ b2,
                           const float* __restrict__ w3, const float* __restrict__ b3,
                           float* __restrict__ out) {
    int gi = blockIdx.x, t = threadIdx.x;
    __shared__ float x[HID];
    __shared__ float y1[HID / 2];
    __shared__ float y2[HID / 4];
    x[t] = g[gi * HID + t];
    __syncthreads();
    if (t < HID / 2) {
        float a = b1[t];
#pragma unroll 8
        for (int k = 0; k < HID; ++k) a += x[k] * w1[k * (HID / 2) + t];
        y1[t] = fmaxf(a, 0.f);
    }
    __syncthreads();
    if (t < HID / 4) {
        float a = b2[t];
#pragma unroll 8
        for (int k = 0; k < HID / 2; ++k) a += y1[k] * w2[k * (HID / 4) + t];
        y2[t] = fmaxf(a, 0.f);
    }
    __syncthreads();
    if (t < 64) {
        float p = y2[t] * w3[t];
#pragma unroll
        for (int off = 32; off > 0; off >>= 1) p += __shfl_down(p, off);
        if (t == 0) out[gi] = p + b3[0];
    }
}

extern "C" void kernel_launch(void* const* d_in, const int* in_sizes, int n_in,
                              void* d_out, int out_size, void* d_ws, size_t ws_size,
                              hipStream_t stream) {
    const float* node_feats = (const float*)d_in[0];
    const int*   src        = (const int*)d_in[1];
    const int*   dst        = (const int*)d_in[2];
    const int*   graph_ids  = (const int*)d_in[3];
    const float* w_embed    = (const float*)d_in[4];
    const float* b_embed    = (const float*)d_in[5];
    const float* gat_W      = (const float*)d_in[6];
    const float* gat_al     = (const float*)d_in[7];
    const float* gat_ar     = (const float*)d_in[8];
    const float* w1         = (const float*)d_in[9];
    const float* b1         = (const float*)d_in[10];
    const float* w2         = (const float*)d_in[11];
    const float* b2         = (const float*)d_in[12];
    const float* w3         = (const float*)d_in[13];
    const float* b3         = (const float*)d_in[14];
    float* out = (float*)d_out;

    char* ws = (char*)d_ws;
    size_t off = 0;
    auto alloc = [&](size_t bytes) { char* p = ws + off; off += (bytes + 15) & ~size_t(15); return p; };
    float*    A      = (float*)alloc((size_t)N_NODES * HID * 4);   // h / h+m
    float*    B      = (float*)alloc((size_t)N_NODES * HID * 4);   // z
    float*    el     = (float*)alloc((size_t)N_NODES * 4);
    float*    er     = (float*)alloc((size_t)N_NODES * 4);
    float*    e      = (float*)alloc((size_t)N_EDGES * 4);
    float*    ex     = (float*)alloc((size_t)N_EDGES * 4);
    unsigned* emax_u = (unsigned*)alloc((size_t)N_NODES * 4);
    float*    esum   = (float*)alloc((size_t)N_NODES * 4);
    float*    g      = (float*)alloc((size_t)N_GRAPHS * HID * 4);

    embed_kernel<<<N_NODES, HID, 0, stream>>>(node_feats, w_embed, b_embed, A);

    for (int l = 0; l < N_GAT; ++l) {
        const float* W  = gat_W  + (size_t)l * HID * HID;
        const float* al = gat_al + (size_t)l * HID;
        const float* ar = gat_ar + (size_t)l * HID;

        node_linear<<<N_NODES, HID, 0, stream>>>(A, W, al, ar, B, el, er);

        hipMemsetAsync(emax_u, 0, (size_t)N_NODES * 4, stream);
        hipMemsetAsync(esum,   0, (size_t)N_NODES * 4, stream);

        edge_max<<<(N_EDGES + 255) / 256, 256, 0, stream>>>(src, dst, el, er, e, emax_u);
        edge_exp<<<(N_EDGES + 255) / 256, 256, 0, stream>>>(dst, e, emax_u, ex, esum);
        edge_scatter<<<N_EDGES, HID, 0, stream>>>(src, dst, ex, esum, B, A);

        int n4 = N_NODES * HID / 4;
        relu4_kernel<<<(n4 + 255) / 256, 256, 0, stream>>>((float4*)A, n4);
    }

    hipMemsetAsync(g, 0, (size_t)N_GRAPHS * HID * 4, stream);
    pool_kernel<<<N_NODES, HID, 0, stream>>>(A, graph_ids, g);

    mlp_kernel<<<N_GRAPHS, HID, 0, stream>>>(g, w1, b1, w2, b2, w3, b3, out);
}

// Round 2
// 1953.886 us; speedup vs baseline: 2.2312x; 2.2312x over previous
//
#include <hip/hip_runtime.h>
#include <hip/hip_bf16.h>

#define N_NODES 100000
#define N_EDGES 200000
#define N_GRAPHS 4096
#define NODE_DIM 64
#define HID 256
#define N_GAT 4
#define NEG_SLOPE 0.2f
#define EPS 1e-9f

__device__ __forceinline__ unsigned f2u(float f) {
    unsigned u = __float_as_uint(f);
    return (u & 0x80000000u) ? ~u : (u | 0x80000000u);
}
__device__ __forceinline__ float u2f(unsigned u) {
    return (u & 0x80000000u) ? __uint_as_float(u & 0x7fffffffu)
                             : __uint_as_float(~u);
}

// Y[N,256] = X[N,K] @ W[K,256] (+bias). One block = TM rows x 256 cols.
// x-tile staged transposed in LDS (pad 20 keeps float4 alignment, spreads banks).
template <int K, int TM, bool BIAS>
__global__ __launch_bounds__(256) void tile_linear(const float* __restrict__ X,
                                                   const float* __restrict__ W,
                                                   const float* __restrict__ bias,
                                                   float* __restrict__ Y) {
    constexpr int PAD = 20;  // >= TM, (PAD*4)%16==0
    __shared__ float xst[K][PAD];
    const int row0 = blockIdx.x * TM;
    const int t = threadIdx.x;

    for (int i = t; i < TM * K; i += 256) {
        int m = i / K, k = i - m * K;
        xst[k][m] = X[(size_t)(row0 + m) * K + k];
    }
    __syncthreads();

    float acc[TM];
#pragma unroll
    for (int m = 0; m < TM; ++m) acc[m] = BIAS ? bias[t] : 0.f;

#pragma unroll 4
    for (int k = 0; k < K; ++k) {
        float w = W[(size_t)k * HID + t];
#pragma unroll
        for (int j = 0; j < TM / 4; ++j) {
            float4 x4 = *(const float4*)&xst[k][4 * j];
            acc[4 * j + 0] = fmaf(x4.x, w, acc[4 * j + 0]);
            acc[4 * j + 1] = fmaf(x4.y, w, acc[4 * j + 1]);
            acc[4 * j + 2] = fmaf(x4.z, w, acc[4 * j + 2]);
            acc[4 * j + 3] = fmaf(x4.w, w, acc[4 * j + 3]);
        }
    }

#pragma unroll
    for (int m = 0; m < TM; ++m)
        Y[(size_t)(row0 + m) * HID + t] = acc[m];
}

// el = z @ al, er = z @ ar. One wave per node.
__global__ void node_dots(const float* __restrict__ z,
                          const float* __restrict__ al,
                          const float* __restrict__ ar,
                          float* __restrict__ el, float* __restrict__ er) {
    int n = blockIdx.x * 4 + (threadIdx.x >> 6);
    int lane = threadIdx.x & 63;
    float4 zz = ((const float4*)(z + (size_t)n * HID))[lane];
    float4 a = ((const float4*)al)[lane];
    float4 b = ((const float4*)ar)[lane];
    float pl = zz.x * a.x + zz.y * a.y + zz.z * a.z + zz.w * a.w;
    float pr = zz.x * b.x + zz.y * b.y + zz.z * b.z + zz.w * b.w;
#pragma unroll
    for (int off = 32; off > 0; off >>= 1) {
        pl += __shfl_down(pl, off);
        pr += __shfl_down(pr, off);
    }
    if (lane == 0) { el[n] = pl; er[n] = pr; }
}

// e = leaky_relu(el[src] + er[dst]); segment max into emax_u (monotone-uint)
__global__ void edge_max(const int* __restrict__ src, const int* __restrict__ dst,
                         const float* __restrict__ el, const float* __restrict__ er,
                         float* __restrict__ e, unsigned* __restrict__ emax_u) {
    int i = blockIdx.x * blockDim.x + threadIdx.x;
    if (i >= N_EDGES) return;
    float v = el[src[i]] + er[dst[i]];
    v = (v >= 0.f) ? v : NEG_SLOPE * v;
    e[i] = v;
    atomicMax(&emax_u[dst[i]], f2u(v));
}

// ex = exp(e - emax[dst]); esum[dst] += ex
__global__ void edge_exp(const int* __restrict__ dst,
                         const float* __restrict__ e,
                         const unsigned* __restrict__ emax_u,
                         float* __restrict__ ex, float* __restrict__ esum) {
    int i = blockIdx.x * blockDim.x + threadIdx.x;
    if (i >= N_EDGES) return;
    int d = dst[i];
    float v = expf(e[i] - u2f(emax_u[d]));
    ex[i] = v;
    atomicAdd(&esum[d], v);
}

// accA[dst,:] += (ex/(esum[dst]+eps)) * z[src,:]   (accA pre-holds h -> residual)
__global__ void edge_scatter(const int* __restrict__ src, const int* __restrict__ dst,
                             const float* __restrict__ ex, const float* __restrict__ esum,
                             const float* __restrict__ z, float* __restrict__ accA) {
    int e = blockIdx.x, t = threadIdx.x;
    int s = src[e], d = dst[e];
    float alpha = ex[e] / (esum[d] + EPS);
    atomicAdd(&accA[d * HID + t], alpha * z[s * HID + t]);
}

__global__ void relu4_kernel(float4* __restrict__ A, int n4) {
    int i = blockIdx.x * blockDim.x + threadIdx.x;
    if (i >= n4) return;
    float4 v = A[i];
    v.x = fmaxf(v.x, 0.f); v.y = fmaxf(v.y, 0.f);
    v.z = fmaxf(v.z, 0.f); v.w = fmaxf(v.w, 0.f);
    A[i] = v;
}

// g[graph_ids[n], :] += h[n, :]
__global__ void pool_kernel(const float* __restrict__ h,
                            const int* __restrict__ gid,
                            float* __restrict__ g) {
    int n = blockIdx.x, t = threadIdx.x;
    atomicAdd(&g[gid[n] * HID + t], h[n * HID + t]);
}

// fused MLP: relu(g@w1+b1) -> relu(@w2+b2) -> @w3+b3
__global__ void mlp_kernel(const float* __restrict__ g,
                           const float* __restrict__ w1, const float* __restrict__ b1,
                           const float* __restrict__ w2, const float* __restrict__ b2,
                           const float* __restrict__ w3, const float* __restrict__ b3,
                           float* __restrict__ out) {
    int gi = blockIdx.x, t = threadIdx.x;
    __shared__ float x[HID];
    __shared__ float y1[HID / 2];
    __shared__ float y2[HID / 4];
    x[t] = g[gi * HID + t];
    __syncthreads();
    if (t < HID / 2) {
        float a = b1[t];
#pragma unroll 8
        for (int k = 0; k < HID; ++k) a += x[k] * w1[k * (HID / 2) + t];
        y1[t] = fmaxf(a, 0.f);
    }
    __syncthreads();
    if (t < HID / 4) {
        float a = b2[t];
#pragma unroll 8
        for (int k = 0; k < HID / 2; ++k) a += y1[k] * w2[k * (HID / 4) + t];
        y2[t] = fmaxf(a, 0.f);
    }
    __syncthreads();
    if (t < 64) {
        float p = y2[t] * w3[t];
#pragma unroll
        for (int off = 32; off > 0; off >>= 1) p += __shfl_down(p, off);
        if (t == 0) out[gi] = p + b3[0];
    }
}

extern "C" void kernel_launch(void* const* d_in, const int* in_sizes, int n_in,
                              void* d_out, int out_size, void* d_ws, size_t ws_size,
                              hipStream_t stream) {
    const float* node_feats = (const float*)d_in[0];
    const int*   src        = (const int*)d_in[1];
    const int*   dst        = (const int*)d_in[2];
    const int*   graph_ids  = (const int*)d_in[3];
    const float* w_embed    = (const float*)d_in[4];
    const float* b_embed    = (const float*)d_in[5];
    const float* gat_W      = (const float*)d_in[6];
    const float* gat_al     = (const float*)d_in[7];
    const float* gat_ar     = (const float*)d_in[8];
    const float* w1         = (const float*)d_in[9];
    const float* b1         = (const float*)d_in[10];
    const float* w2         = (const float*)d_in[11];
    const float* b2         = (const float*)d_in[12];
    const float* w3         = (const float*)d_in[13];
    const float* b3         = (const float*)d_in[14];
    float* out = (float*)d_out;

    char* ws = (char*)d_ws;
    size_t off = 0;
    auto alloc = [&](size_t bytes) { char* p = ws + off; off += (bytes + 15) & ~size_t(15); return p; };
    float*    A      = (float*)alloc((size_t)N_NODES * HID * 4);   // h / h+m
    float*    B      = (float*)alloc((size_t)N_NODES * HID * 4);   // z
    float*    el     = (float*)alloc((size_t)N_NODES * 4);
    float*    er     = (float*)alloc((size_t)N_NODES * 4);
    float*    e      = (float*)alloc((size_t)N_EDGES * 4);
    float*    ex     = (float*)alloc((size_t)N_EDGES * 4);
    unsigned* emax_u = (unsigned*)alloc((size_t)N_NODES * 4);
    float*    esum   = (float*)alloc((size_t)N_NODES * 4);
    float*    g      = (float*)alloc((size_t)N_GRAPHS * HID * 4);

    constexpr int TM = 16;
    tile_linear<NODE_DIM, TM, true><<<N_NODES / TM, 256, 0, stream>>>(node_feats, w_embed, b_embed, A);

    for (int l = 0; l < N_GAT; ++l) {
        const float* W  = gat_W  + (size_t)l * HID * HID;
        const float* al = gat_al + (size_t)l * HID;
        const float* ar = gat_ar + (size_t)l * HID;

        tile_linear<HID, TM, false><<<N_NODES / TM, 256, 0, stream>>>(A, W, nullptr, B);
        node_dots<<<N_NODES / 4, 256, 0, stream>>>(B, al, ar, el, er);

        hipMemsetAsync(emax_u, 0, (size_t)N_NODES * 4, stream);
        hipMemsetAsync(esum,   0, (size_t)N_NODES * 4, stream);

        edge_max<<<(N_EDGES + 255) / 256, 256, 0, stream>>>(src, dst, el, er, e, emax_u);
        edge_exp<<<(N_EDGES + 255) / 256, 256, 0, stream>>>(dst, e, emax_u, ex, esum);
        edge_scatter<<<N_EDGES, HID, 0, stream>>>(src, dst, ex, esum, B, A);

        int n4 = N_NODES * HID / 4;
        relu4_kernel<<<(n4 + 255) / 256, 256, 0, stream>>>((float4*)A, n4);
    }

    hipMemsetAsync(g, 0, (size_t)N_GRAPHS * HID * 4, stream);
    pool_kernel<<<N_NODES, HID, 0, stream>>>(A, graph_ids, g);

    mlp_kernel<<<N_GRAPHS, HID, 0, stream>>>(g, w1, b1, w2, b2, w3, b3, out);
}

// Round 3
// 1785.942 us; speedup vs baseline: 2.4410x; 1.0940x over previous
//
#include <hip/hip_runtime.h>
#include <hip/hip_bf16.h>

#define N_NODES 100000
#define N_EDGES 200000
#define N_GRAPHS 4096
#define NODE_DIM 64
#define HID 256
#define N_GAT 4
#define NEG_SLOPE 0.2f
#define EPS 1e-9f

__device__ __forceinline__ unsigned f2u(float f) {
    unsigned u = __float_as_uint(f);
    return (u & 0x80000000u) ? ~u : (u | 0x80000000u);
}
__device__ __forceinline__ float u2f(unsigned u) {
    return (u & 0x80000000u) ? __uint_as_float(u & 0x7fffffffu)
                             : __uint_as_float(~u);
}

typedef const __attribute__((address_space(1))) void gv_t;
typedef __attribute__((address_space(3))) void lv_t;

// Y[M,256] = X[M,K] @ W[K,256] (+bias).
// Block tile 128x128, thread tile 8x8 (16x16 thread grid), KC=32 chunks.
// Staging via global_load_lds width-16 (linear LDS layouts):
//   xs: [row][32] row-major; ws: [k][128] row-major.
template <int K, bool BIAS>
__global__ __launch_bounds__(256) void gemm_tile(const float* __restrict__ X,
                                                 const float* __restrict__ W,
                                                 const float* __restrict__ bias,
                                                 float* __restrict__ Y, int M) {
    constexpr int KC = 32;
    __shared__ float xs[128 * KC];   // row*32 + k
    __shared__ float ws[KC * 128];   // k*128 + c
    const int t  = threadIdx.x;
    const int wv = t >> 6;           // wave id (uniform per wave)
    const int ln = t & 63;
    const int tr = t >> 4;           // 0..15 row-thread
    const int tc = t & 15;           // 0..15 col-thread
    const long row0 = (long)blockIdx.x * 128;
    const int  col0 = blockIdx.y * 128;

    float acc[8][8];
#pragma unroll
    for (int i = 0; i < 8; ++i)
#pragma unroll
        for (int j = 0; j < 8; ++j) acc[i][j] = 0.f;

    for (int k0 = 0; k0 < K; k0 += KC) {
        // ---- stage X tile: 128 rows x 32 k = 16KB, 16 glds (4/wave) ----
#pragma unroll
        for (int i = 0; i < 4; ++i) {
            const int base = (wv * 4 + i) * 256;           // float offset in xs
            const int row  = (base >> 5) + (ln >> 3);      // 0..127
            long gr = row0 + row;
            if (gr >= M) gr = M - 1;                        // clamp tail (unused rows)
            const float* gp = X + gr * K + (k0 + 4 * (ln & 7));
            __builtin_amdgcn_global_load_lds((gv_t*)gp, (lv_t*)(xs + base), 16, 0, 0);
        }
        // ---- stage W tile: 32 k x 128 cols = 16KB, 16 glds (4/wave) ----
#pragma unroll
        for (int i = 0; i < 4; ++i) {
            const int base = (wv * 4 + i) * 256;           // float offset in ws
            const int kk   = (base >> 7) + (ln >> 5);      // 0..31
            const float* gp = W + (size_t)(k0 + kk) * HID + (col0 + 4 * (ln & 31));
            __builtin_amdgcn_global_load_lds((gv_t*)gp, (lv_t*)(ws + base), 16, 0, 0);
        }
        __syncthreads();   // drains vmcnt + lgkmcnt

#pragma unroll 8
        for (int k = 0; k < KC; ++k) {
            float4 w0 = *(const float4*)&ws[k * 128 + tc * 4];
            float4 w1 = *(const float4*)&ws[k * 128 + 64 + tc * 4];
            float xv[8];
#pragma unroll
            for (int i = 0; i < 4; ++i) {
                xv[i]     = xs[(tr * 4 + i) * KC + k];
                xv[i + 4] = xs[(64 + tr * 4 + i) * KC + k];
            }
            float wvv[8] = {w0.x, w0.y, w0.z, w0.w, w1.x, w1.y, w1.z, w1.w};
#pragma unroll
            for (int i = 0; i < 8; ++i)
#pragma unroll
                for (int j = 0; j < 8; ++j)
                    acc[i][j] = fmaf(xv[i], wvv[j], acc[i][j]);
        }
        __syncthreads();
    }

    float bj[8];
#pragma unroll
    for (int j = 0; j < 8; ++j)
        bj[j] = BIAS ? bias[col0 + ((j < 4) ? (tc * 4 + j) : (64 + tc * 4 + j - 4))] : 0.f;

#pragma unroll
    for (int i = 0; i < 8; ++i) {
        long r = row0 + ((i < 4) ? (tr * 4 + i) : (64 + tr * 4 + i - 4));
        if (r >= M) continue;
        float4 o0 = make_float4(acc[i][0] + bj[0], acc[i][1] + bj[1],
                                acc[i][2] + bj[2], acc[i][3] + bj[3]);
        float4 o1 = make_float4(acc[i][4] + bj[4], acc[i][5] + bj[5],
                                acc[i][6] + bj[6], acc[i][7] + bj[7]);
        *(float4*)&Y[r * HID + col0 + tc * 4]      = o0;
        *(float4*)&Y[r * HID + col0 + 64 + tc * 4] = o1;
    }
}

// el = z @ al, er = z @ ar. One wave per node.
__global__ void node_dots(const float* __restrict__ z,
                          const float* __restrict__ al,
                          const float* __restrict__ ar,
                          float* __restrict__ el, float* __restrict__ er) {
    int n = blockIdx.x * 4 + (threadIdx.x >> 6);
    int lane = threadIdx.x & 63;
    float4 zz = ((const float4*)(z + (size_t)n * HID))[lane];
    float4 a = ((const float4*)al)[lane];
    float4 b = ((const float4*)ar)[lane];
    float pl = zz.x * a.x + zz.y * a.y + zz.z * a.z + zz.w * a.w;
    float pr = zz.x * b.x + zz.y * b.y + zz.z * b.z + zz.w * b.w;
#pragma unroll
    for (int off = 32; off > 0; off >>= 1) {
        pl += __shfl_down(pl, off);
        pr += __shfl_down(pr, off);
    }
    if (lane == 0) { el[n] = pl; er[n] = pr; }
}

// e = leaky_relu(el[src] + er[dst]); segment max into emax_u (monotone-uint)
__global__ void edge_max(const int* __restrict__ src, const int* __restrict__ dst,
                         const float* __restrict__ el, const float* __restrict__ er,
                         float* __restrict__ e, unsigned* __restrict__ emax_u) {
    int i = blockIdx.x * blockDim.x + threadIdx.x;
    if (i >= N_EDGES) return;
    float v = el[src[i]] + er[dst[i]];
    v = (v >= 0.f) ? v : NEG_SLOPE * v;
    e[i] = v;
    atomicMax(&emax_u[dst[i]], f2u(v));
}

// ex = exp(e - emax[dst]); esum[dst] += ex
__global__ void edge_exp(const int* __restrict__ dst,
                         const float* __restrict__ e,
                         const unsigned* __restrict__ emax_u,
                         float* __restrict__ ex, float* __restrict__ esum) {
    int i = blockIdx.x * blockDim.x + threadIdx.x;
    if (i >= N_EDGES) return;
    int d = dst[i];
    float v = expf(e[i] - u2f(emax_u[d]));
    ex[i] = v;
    atomicAdd(&esum[d], v);
}

// accA[dst,:] += (ex/(esum[dst]+eps)) * z[src,:]   (accA pre-holds h -> residual)
__global__ void edge_scatter(const int* __restrict__ src, const int* __restrict__ dst,
                             const float* __restrict__ ex, const float* __restrict__ esum,
                             const float* __restrict__ z, float* __restrict__ accA) {
    int e = blockIdx.x, t = threadIdx.x;
    int s = src[e], d = dst[e];
    float alpha = ex[e] / (esum[d] + EPS);
    atomicAdd(&accA[d * HID + t], alpha * z[s * HID + t]);
}

__global__ void relu4_kernel(float4* __restrict__ A, int n4) {
    int i = blockIdx.x * blockDim.x + threadIdx.x;
    if (i >= n4) return;
    float4 v = A[i];
    v.x = fmaxf(v.x, 0.f); v.y = fmaxf(v.y, 0.f);
    v.z = fmaxf(v.z, 0.f); v.w = fmaxf(v.w, 0.f);
    A[i] = v;
}

// g[graph_ids[n], :] += h[n, :]
__global__ void pool_kernel(const float* __restrict__ h,
                            const int* __restrict__ gid,
                            float* __restrict__ g) {
    int n = blockIdx.x, t = threadIdx.x;
    atomicAdd(&g[gid[n] * HID + t], h[n * HID + t]);
}

// fused MLP: relu(g@w1+b1) -> relu(@w2+b2) -> @w3+b3
__global__ void mlp_kernel(const float* __restrict__ g,
                           const float* __restrict__ w1, const float* __restrict__ b1,
                           const float* __restrict__ w2, const float* __restrict__ b2,
                           const float* __restrict__ w3, const float* __restrict__ b3,
                           float* __restrict__ out) {
    int gi = blockIdx.x, t = threadIdx.x;
    __shared__ float x[HID];
    __shared__ float y1[HID / 2];
    __shared__ float y2[HID / 4];
    x[t] = g[gi * HID + t];
    __syncthreads();
    if (t < HID / 2) {
        float a = b1[t];
#pragma unroll 8
        for (int k = 0; k < HID; ++k) a += x[k] * w1[k * (HID / 2) + t];
        y1[t] = fmaxf(a, 0.f);
    }
    __syncthreads();
    if (t < HID / 4) {
        float a = b2[t];
#pragma unroll 8
        for (int k = 0; k < HID / 2; ++k) a += y1[k] * w2[k * (HID / 4) + t];
        y2[t] = fmaxf(a, 0.f);
    }
    __syncthreads();
    if (t < 64) {
        float p = y2[t] * w3[t];
#pragma unroll
        for (int off = 32; off > 0; off >>= 1) p += __shfl_down(p, off);
        if (t == 0) out[gi] = p + b3[0];
    }
}

extern "C" void kernel_launch(void* const* d_in, const int* in_sizes, int n_in,
                              void* d_out, int out_size, void* d_ws, size_t ws_size,
                              hipStream_t stream) {
    const float* node_feats = (const float*)d_in[0];
    const int*   src        = (const int*)d_in[1];
    const int*   dst        = (const int*)d_in[2];
    const int*   graph_ids  = (const int*)d_in[3];
    const float* w_embed    = (const float*)d_in[4];
    const float* b_embed    = (const float*)d_in[5];
    const float* gat_W      = (const float*)d_in[6];
    const float* gat_al     = (const float*)d_in[7];
    const float* gat_ar     = (const float*)d_in[8];
    const float* w1         = (const float*)d_in[9];
    const float* b1         = (const float*)d_in[10];
    const float* w2         = (const float*)d_in[11];
    const float* b2         = (const float*)d_in[12];
    const float* w3         = (const float*)d_in[13];
    const float* b3         = (const float*)d_in[14];
    float* out = (float*)d_out;

    char* ws = (char*)d_ws;
    size_t off = 0;
    auto alloc = [&](size_t bytes) { char* p = ws + off; off += (bytes + 15) & ~size_t(15); return p; };
    float*    A      = (float*)alloc((size_t)N_NODES * HID * 4);   // h / h+m
    float*    B      = (float*)alloc((size_t)N_NODES * HID * 4);   // z
    float*    el     = (float*)alloc((size_t)N_NODES * 4);
    float*    er     = (float*)alloc((size_t)N_NODES * 4);
    float*    e      = (float*)alloc((size_t)N_EDGES * 4);
    float*    ex     = (float*)alloc((size_t)N_EDGES * 4);
    unsigned* emax_u = (unsigned*)alloc((size_t)N_NODES * 4);
    float*    esum   = (float*)alloc((size_t)N_NODES * 4);
    float*    g      = (float*)alloc((size_t)N_GRAPHS * HID * 4);

    dim3 ggrid((N_NODES + 127) / 128, HID / 128);
    gemm_tile<NODE_DIM, true><<<ggrid, 256, 0, stream>>>(node_feats, w_embed, b_embed, A, N_NODES);

    for (int l = 0; l < N_GAT; ++l) {
        const float* W  = gat_W  + (size_t)l * HID * HID;
        const float* al = gat_al + (size_t)l * HID;
        const float* ar = gat_ar + (size_t)l * HID;

        gemm_tile<HID, false><<<ggrid, 256, 0, stream>>>(A, W, nullptr, B, N_NODES);
        node_dots<<<N_NODES / 4, 256, 0, stream>>>(B, al, ar, el, er);

        hipMemsetAsync(emax_u, 0, (size_t)N_NODES * 4, stream);
        hipMemsetAsync(esum,   0, (size_t)N_NODES * 4, stream);

        edge_max<<<(N_EDGES + 255) / 256, 256, 0, stream>>>(src, dst, el, er, e, emax_u);
        edge_exp<<<(N_EDGES + 255) / 256, 256, 0, stream>>>(dst, e, emax_u, ex, esum);
        edge_scatter<<<N_EDGES, HID, 0, stream>>>(src, dst, ex, esum, B, A);

        int n4 = N_NODES * HID / 4;
        relu4_kernel<<<(n4 + 255) / 256, 256, 0, stream>>>((float4*)A, n4);
    }

    hipMemsetAsync(g, 0, (size_t)N_GRAPHS * HID * 4, stream);
    pool_kernel<<<N_NODES, HID, 0, stream>>>(A, graph_ids, g);

    mlp_kernel<<<N_GRAPHS, HID, 0, stream>>>(g, w1, b1, w2, b2, w3, b3, out);
}

// Round 4
// 1258.334 us; speedup vs baseline: 3.4645x; 1.4193x over previous
//
#include <hip/hip_runtime.h>
#include <hip/hip_bf16.h>

#define N_NODES 100000
#define N_EDGES 200000
#define N_GRAPHS 4096
#define NODE_DIM 64
#define HID 256
#define N_GAT 4
#define NEG_SLOPE 0.2f
#define EPS 1e-9f
#define NB 98  // ceil(N_NODES/1024)

typedef const __attribute__((address_space(1))) void gv_t;
typedef __attribute__((address_space(3))) void lv_t;

// ============================ GEMM ============================
// Y[M,256] = X[M,K] @ W[K,256] (+bias).
// Block tile 128x128, thread tile 8x8, KC=32.
// xs is XOR-swizzled at 16B granularity: row r, granule g stored at g^((r>>1)&7).
// Swizzle applied on the GLOBAL source address (global_load_lds dest is linear).
template <int K, bool BIAS>
__global__ __launch_bounds__(256) void gemm_tile(const float* __restrict__ X,
                                                 const float* __restrict__ W,
                                                 const float* __restrict__ bias,
                                                 float* __restrict__ Y, int M) {
    constexpr int KC = 32;
    __shared__ float xs[128 * KC];   // swizzled [row][32]
    __shared__ float ws[KC * 128];   // k*128 + c (linear)
    const int t  = threadIdx.x;
    const int wv = t >> 6;
    const int ln = t & 63;
    const int tr = t >> 4;           // 0..15
    const int tc = t & 15;           // 0..15
    const long row0 = (long)blockIdx.x * 128;
    const int  col0 = blockIdx.y * 128;

    float acc[8][8];
#pragma unroll
    for (int i = 0; i < 8; ++i)
#pragma unroll
        for (int j = 0; j < 8; ++j) acc[i][j] = 0.f;

    for (int k0 = 0; k0 < K; k0 += KC) {
        // ---- stage X tile (swizzled source) ----
#pragma unroll
        for (int i = 0; i < 4; ++i) {
            const int base = (wv * 4 + i) * 256;
            const int row  = (base >> 5) + (ln >> 3);      // 0..127 LDS row
            const int g    = (ln & 7) ^ ((row >> 1) & 7);  // swizzled k-granule
            long gr = row0 + row;
            if (gr >= M) gr = M - 1;
            const float* gp = X + gr * K + (k0 + 4 * g);
            __builtin_amdgcn_global_load_lds((gv_t*)gp, (lv_t*)(xs + base), 16, 0, 0);
        }
        // ---- stage W tile (linear) ----
#pragma unroll
        for (int i = 0; i < 4; ++i) {
            const int base = (wv * 4 + i) * 256;
            const int kk   = (base >> 7) + (ln >> 5);
            const float* gp = W + (size_t)(k0 + kk) * HID + (col0 + 4 * (ln & 31));
            __builtin_amdgcn_global_load_lds((gv_t*)gp, (lv_t*)(ws + base), 16, 0, 0);
        }
        __syncthreads();

#pragma unroll 8
        for (int k = 0; k < KC; ++k) {
            float4 w0 = *(const float4*)&ws[k * 128 + tc * 4];
            float4 w1 = *(const float4*)&ws[k * 128 + 64 + tc * 4];
            float xv[8];
#pragma unroll
            for (int i = 0; i < 4; ++i) {
                const int rsw = ((tr * 4 + i) >> 1) & 7;   // same for row and row+64
                const int ko  = ((((k >> 2) ^ rsw) << 2) | (k & 3));
                xv[i]     = xs[(tr * 4 + i) * KC + ko];
                xv[i + 4] = xs[(64 + tr * 4 + i) * KC + ko];
            }
            float wvv[8] = {w0.x, w0.y, w0.z, w0.w, w1.x, w1.y, w1.z, w1.w};
#pragma unroll
            for (int i = 0; i < 8; ++i)
#pragma unroll
                for (int j = 0; j < 8; ++j)
                    acc[i][j] = fmaf(xv[i], wvv[j], acc[i][j]);
        }
        __syncthreads();
    }

    float bj[8];
#pragma unroll
    for (int j = 0; j < 8; ++j)
        bj[j] = BIAS ? bias[col0 + ((j < 4) ? (tc * 4 + j) : (64 + tc * 4 + j - 4))] : 0.f;

#pragma unroll
    for (int i = 0; i < 8; ++i) {
        long r = row0 + ((i < 4) ? (tr * 4 + i) : (64 + tr * 4 + i - 4));
        if (r >= M) continue;
        float4 o0 = make_float4(acc[i][0] + bj[0], acc[i][1] + bj[1],
                                acc[i][2] + bj[2], acc[i][3] + bj[3]);
        float4 o1 = make_float4(acc[i][4] + bj[4], acc[i][5] + bj[5],
                                acc[i][6] + bj[6], acc[i][7] + bj[7]);
        *(float4*)&Y[r * HID + col0 + tc * 4]      = o0;
        *(float4*)&Y[r * HID + col0 + 64 + tc * 4] = o1;
    }
}

// ======================= CSR build (per launch) =======================
__global__ void hist_dst(const int* __restrict__ dst, int* __restrict__ deg) {
    int i = blockIdx.x * 256 + threadIdx.x;
    if (i < N_EDGES) atomicAdd(&deg[dst[i]], 1);
}

__global__ __launch_bounds__(1024) void scan_block(const int* __restrict__ deg,
                                                   int* __restrict__ sexc,
                                                   int* __restrict__ bsum) {
    int t = threadIdx.x, gid = blockIdx.x * 1024 + t;
    int v = (gid < N_NODES) ? deg[gid] : 0;
    int lane = t & 63, wv = t >> 6;
    int x = v;
#pragma unroll
    for (int o = 1; o < 64; o <<= 1) {
        int y = __shfl_up(x, o);
        if (lane >= o) x += y;
    }
    __shared__ int wsum[16];
    if (lane == 63) wsum[wv] = x;
    __syncthreads();
    if (t == 0) {
        int a = 0;
#pragma unroll
        for (int i = 0; i < 16; ++i) { int tt = wsum[i]; wsum[i] = a; a += tt; }
        bsum[blockIdx.x] = a;
    }
    __syncthreads();
    sexc[gid] = (x - v) + wsum[wv];
}

__global__ __launch_bounds__(128) void scan_partials(int* __restrict__ bsum,
                                                     int* __restrict__ offsets) {
    __shared__ int s[128];
    int t = threadIdx.x;
    int v = (t < NB) ? bsum[t] : 0;
    s[t] = v;
    __syncthreads();
    for (int o = 1; o < 128; o <<= 1) {
        int y = (t >= o) ? s[t - o] : 0;
        __syncthreads();
        s[t] += y;
        __syncthreads();
    }
    if (t < NB) bsum[t] = s[t] - v;          // exclusive
    if (t == 127) offsets[N_NODES] = s[127]; // total (=N_EDGES)
}

__global__ __launch_bounds__(1024) void scan_add(const int* __restrict__ sexc,
                                                 const int* __restrict__ bsum,
                                                 int* __restrict__ offsets) {
    int gid = blockIdx.x * 1024 + threadIdx.x;
    if (gid < N_NODES) offsets[gid] = sexc[gid] + bsum[blockIdx.x];
}

__global__ void csr_fill(const int* __restrict__ src, const int* __restrict__ dst,
                         const int* __restrict__ offsets, int* __restrict__ cnt,
                         int* __restrict__ csrc) {
    int i = blockIdx.x * 256 + threadIdx.x;
    if (i < N_EDGES) {
        int d = dst[i];
        int slot = offsets[d] + atomicAdd(&cnt[d], 1);
        csrc[slot] = src[i];
    }
}

// ===================== per-layer small kernels =====================
// el = z @ al, er = z @ ar. One wave per node.
__global__ void node_dots(const float* __restrict__ z,
                          const float* __restrict__ al,
                          const float* __restrict__ ar,
                          float* __restrict__ el, float* __restrict__ er) {
    int n = blockIdx.x * 4 + (threadIdx.x >> 6);
    int lane = threadIdx.x & 63;
    float4 zz = ((const float4*)(z + (size_t)n * HID))[lane];
    float4 a = ((const float4*)al)[lane];
    float4 b = ((const float4*)ar)[lane];
    float pl = zz.x * a.x + zz.y * a.y + zz.z * a.z + zz.w * a.w;
    float pr = zz.x * b.x + zz.y * b.y + zz.z * b.z + zz.w * b.w;
#pragma unroll
    for (int off = 32; off > 0; off >>= 1) {
        pl += __shfl_down(pl, off);
        pr += __shfl_down(pr, off);
    }
    if (lane == 0) { el[n] = pl; er[n] = pr; }
}

// One wave per dst node: segment softmax + alpha-weighted z gather +
// residual + ReLU. No atomics. Replaces edge_max/edge_exp/edge_scatter/relu4.
__global__ __launch_bounds__(256) void fused_attn(const int* __restrict__ offs,
                                                  const int* __restrict__ csrc,
                                                  const float* __restrict__ el,
                                                  const float* __restrict__ er,
                                                  const float* __restrict__ z,
                                                  float* __restrict__ A) {
    const int n = blockIdx.x * 4 + (threadIdx.x >> 6);
    const int lane = threadIdx.x & 63;
    const int beg = offs[n], end = offs[n + 1];
    const float ern = er[n];

    // pass 1: segment max
    float m = -3.4e38f;
    for (int c = beg + lane; c < end; c += 64) {
        float v = el[csrc[c]] + ern;
        v = (v >= 0.f) ? v : NEG_SLOPE * v;
        m = fmaxf(m, v);
    }
#pragma unroll
    for (int o = 32; o > 0; o >>= 1) m = fmaxf(m, __shfl_xor(m, o));

    // pass 2: exp-sum
    float s = 0.f;
    for (int c = beg + lane; c < end; c += 64) {
        float v = el[csrc[c]] + ern;
        v = (v >= 0.f) ? v : NEG_SLOPE * v;
        s += __expf(v - m);
    }
#pragma unroll
    for (int o = 32; o > 0; o >>= 1) s += __shfl_xor(s, o);
    const float inv = 1.f / (s + EPS);

    // pass 3: weighted gather (wave-uniform edge loop, coalesced 1KB z rows)
    float4 acc = make_float4(0.f, 0.f, 0.f, 0.f);
    for (int c = beg; c < end; ++c) {
        int sc = csrc[c];                       // uniform -> broadcast
        float v = el[sc] + ern;
        v = (v >= 0.f) ? v : NEG_SLOPE * v;
        float alpha = __expf(v - m) * inv;
        float4 zz = ((const float4*)(z + (size_t)sc * HID))[lane];
        acc.x = fmaf(alpha, zz.x, acc.x);
        acc.y = fmaf(alpha, zz.y, acc.y);
        acc.z = fmaf(alpha, zz.z, acc.z);
        acc.w = fmaf(alpha, zz.w, acc.w);
    }

    // residual + ReLU
    float4* Ap = (float4*)(A + (size_t)n * HID);
    float4 h4 = Ap[lane];
    h4.x = fmaxf(h4.x + acc.x, 0.f);
    h4.y = fmaxf(h4.y + acc.y, 0.f);
    h4.z = fmaxf(h4.z + acc.z, 0.f);
    h4.w = fmaxf(h4.w + acc.w, 0.f);
    Ap[lane] = h4;
}

// g[graph_ids[n], :] += h[n, :]
__global__ void pool_kernel(const float* __restrict__ h,
                            const int* __restrict__ gid,
                            float* __restrict__ g) {
    int n = blockIdx.x, t = threadIdx.x;
    atomicAdd(&g[gid[n] * HID + t], h[n * HID + t]);
}

// fused MLP: relu(g@w1+b1) -> relu(@w2+b2) -> @w3+b3
__global__ void mlp_kernel(const float* __restrict__ g,
                           const float* __restrict__ w1, const float* __restrict__ b1,
                           const float* __restrict__ w2, const float* __restrict__ b2,
                           const float* __restrict__ w3, const float* __restrict__ b3,
                           float* __restrict__ out) {
    int gi = blockIdx.x, t = threadIdx.x;
    __shared__ float x[HID];
    __shared__ float y1[HID / 2];
    __shared__ float y2[HID / 4];
    x[t] = g[gi * HID + t];
    __syncthreads();
    if (t < HID / 2) {
        float a = b1[t];
#pragma unroll 8
        for (int k = 0; k < HID; ++k) a += x[k] * w1[k * (HID / 2) + t];
        y1[t] = fmaxf(a, 0.f);
    }
    __syncthreads();
    if (t < HID / 4) {
        float a = b2[t];
#pragma unroll 8
        for (int k = 0; k < HID / 2; ++k) a += y1[k] * w2[k * (HID / 4) + t];
        y2[t] = fmaxf(a, 0.f);
    }
    __syncthreads();
    if (t < 64) {
        float p = y2[t] * w3[t];
#pragma unroll
        for (int off = 32; off > 0; off >>= 1) p += __shfl_down(p, off);
        if (t == 0) out[gi] = p + b3[0];
    }
}

extern "C" void kernel_launch(void* const* d_in, const int* in_sizes, int n_in,
                              void* d_out, int out_size, void* d_ws, size_t ws_size,
                              hipStream_t stream) {
    const float* node_feats = (const float*)d_in[0];
    const int*   src        = (const int*)d_in[1];
    const int*   dst        = (const int*)d_in[2];
    const int*   graph_ids  = (const int*)d_in[3];
    const float* w_embed    = (const float*)d_in[4];
    const float* b_embed    = (const float*)d_in[5];
    const float* gat_W      = (const float*)d_in[6];
    const float* gat_al     = (const float*)d_in[7];
    const float* gat_ar     = (const float*)d_in[8];
    const float* w1         = (const float*)d_in[9];
    const float* b1         = (const float*)d_in[10];
    const float* w2         = (const float*)d_in[11];
    const float* b2         = (const float*)d_in[12];
    const float* w3         = (const float*)d_in[13];
    const float* b3         = (const float*)d_in[14];
    float* out = (float*)d_out;

    char* ws = (char*)d_ws;
    size_t off = 0;
    auto alloc = [&](size_t bytes) { char* p = ws + off; off += (bytes + 15) & ~size_t(15); return p; };
    float* A       = (float*)alloc((size_t)N_NODES * HID * 4);   // h
    float* B       = (float*)alloc((size_t)N_NODES * HID * 4);   // z
    float* el      = (float*)alloc((size_t)N_NODES * 4);
    float* er      = (float*)alloc((size_t)N_NODES * 4);
    int*   deg     = (int*)alloc((size_t)N_NODES * 4);
    int*   cnt     = (int*)alloc((size_t)N_NODES * 4);
    int*   sexc    = (int*)alloc((size_t)NB * 1024 * 4);
    int*   bsum    = (int*)alloc(128 * 4);
    int*   offsets = (int*)alloc((size_t)(N_NODES + 1) * 4);
    int*   csrc    = (int*)alloc((size_t)N_EDGES * 4);
    float* g       = (float*)alloc((size_t)N_GRAPHS * HID * 4);

    // ---- CSR build (graph is static across layers) ----
    hipMemsetAsync(deg, 0, (size_t)N_NODES * 4, stream);
    hipMemsetAsync(cnt, 0, (size_t)N_NODES * 4, stream);
    hist_dst<<<(N_EDGES + 255) / 256, 256, 0, stream>>>(dst, deg);
    scan_block<<<NB, 1024, 0, stream>>>(deg, sexc, bsum);
    scan_partials<<<1, 128, 0, stream>>>(bsum, offsets);
    scan_add<<<NB, 1024, 0, stream>>>(sexc, bsum, offsets);
    csr_fill<<<(N_EDGES + 255) / 256, 256, 0, stream>>>(src, dst, offsets, cnt, csrc);

    dim3 ggrid((N_NODES + 127) / 128, HID / 128);
    gemm_tile<NODE_DIM, true><<<ggrid, 256, 0, stream>>>(node_feats, w_embed, b_embed, A, N_NODES);

    for (int l = 0; l < N_GAT; ++l) {
        const float* W  = gat_W  + (size_t)l * HID * HID;
        const float* al = gat_al + (size_t)l * HID;
        const float* ar = gat_ar + (size_t)l * HID;

        gemm_tile<HID, false><<<ggrid, 256, 0, stream>>>(A, W, nullptr, B, N_NODES);
        node_dots<<<N_NODES / 4, 256, 0, stream>>>(B, al, ar, el, er);
        fused_attn<<<N_NODES / 4, 256, 0, stream>>>(offsets, csrc, el, er, B, A);
    }

    hipMemsetAsync(g, 0, (size_t)N_GRAPHS * HID * 4, stream);
    pool_kernel<<<N_NODES, HID, 0, stream>>>(A, graph_ids, g);

    mlp_kernel<<<N_GRAPHS, HID, 0, stream>>>(g, w1, b1, w2, b2, w3, b3, out);
}

// Round 5
// 647.937 us; speedup vs baseline: 6.7282x; 1.9421x over previous
//
#include <hip/hip_runtime.h>
#include <hip/hip_bf16.h>

#define N_NODES 100000
#define N_EDGES 200000
#define N_GRAPHS 4096
#define NODE_DIM 64
#define HID 256
#define N_GAT 4
#define NEG_SLOPE 0.2f
#define EPS 1e-9f
#define NB 98  // ceil(N_NODES/1024)

typedef const __attribute__((address_space(1))) void gv_t;
typedef __attribute__((address_space(3))) void lv_t;
typedef __attribute__((ext_vector_type(8))) short bf16x8;
typedef __attribute__((ext_vector_type(4))) float f32x4;

__device__ __forceinline__ float b2f(unsigned short u) {
    return __uint_as_float(((unsigned)u) << 16);
}
__device__ __forceinline__ unsigned short f2b(float f) {   // RNE
    unsigned u = __float_as_uint(f);
    return (unsigned short)((u + 0x7fffu + ((u >> 16) & 1u)) >> 16);
}

// ==================== converters ====================
__global__ void convert_f32_bf16(const float* __restrict__ src,
                                 unsigned short* __restrict__ dst, int n4) {
    int i = blockIdx.x * 256 + threadIdx.x;
    if (i >= n4) return;
    float4 v = ((const float4*)src)[i];
    ushort4 o;
    o.x = f2b(v.x); o.y = f2b(v.y); o.z = f2b(v.z); o.w = f2b(v.w);
    ((ushort4*)dst)[i] = o;
}

// Wt[c][k] = bf16(W[k][c]);  W is [K][256], Wt is [256][K]
__global__ __launch_bounds__(256) void transpose_bf16(const float* __restrict__ W,
                                                      unsigned short* __restrict__ Wt,
                                                      int K) {
    __shared__ float tile[32][33];
    const int kb = blockIdx.x * 32, cb = blockIdx.y * 32;
    const int tr = threadIdx.x >> 5, tc = threadIdx.x & 31;
#pragma unroll
    for (int i = 0; i < 4; ++i)
        tile[tr + i * 8][tc] = W[(size_t)(kb + tr + i * 8) * HID + cb + tc];
    __syncthreads();
#pragma unroll
    for (int i = 0; i < 4; ++i)
        Wt[(size_t)(cb + tr + i * 8) * K + kb + tc] = f2b(tile[tc][tr + i * 8]);
}

// ==================== MFMA GEMM ====================
// Y[M,256] = X[M,K](bf16) @ Wt[256,K](bf16, pre-transposed) (+bias).
// 128x128 block tile, 4 waves (64x64 each), 4x4 frags of 16x16x32 bf16 MFMA.
// Both LDS tiles [row][KC] with 16B-granule XOR swizzle (g ^= row&7), applied
// on the GLOBAL source address (global_load_lds dest stays linear).
template <int K, bool BIAS, bool OUTF32, bool OUTBF16>
__global__ __launch_bounds__(256) void gemm_mfma(const unsigned short* __restrict__ Xb,
                                                 const unsigned short* __restrict__ Wt,
                                                 const float* __restrict__ bias,
                                                 float* __restrict__ Yf,
                                                 unsigned short* __restrict__ Yb,
                                                 int M) {
    constexpr int KC = 64;
    __shared__ unsigned short xs[128 * KC];   // [row][64] bf16, swizzled granules
    __shared__ unsigned short wsx[128 * KC];  // [col][64] bf16, swizzled granules
    const int t = threadIdx.x, wv = t >> 6, ln = t & 63;
    const int wr2 = wv >> 1, wc2 = wv & 1;    // wave quadrant (2x2)
    const long row0 = (long)blockIdx.x * 128;
    const int  col0 = blockIdx.y * 128;

    f32x4 acc[4][4];
#pragma unroll
    for (int m = 0; m < 4; ++m)
#pragma unroll
        for (int n = 0; n < 4; ++n) acc[m][n] = (f32x4){0.f, 0.f, 0.f, 0.f};

    for (int k0 = 0; k0 < K; k0 += KC) {
        // stage X tile: 16 chunks of 1KB (8 rows each), 4 per wave
#pragma unroll
        for (int i = 0; i < 4; ++i) {
            const int chunk = wv * 4 + i;
            const int row = chunk * 8 + (ln >> 3);
            const int gsrc = (ln & 7) ^ (row & 7);
            long gr = row0 + row; if (gr >= M) gr = M - 1;
            const unsigned short* gp = Xb + gr * K + k0 + gsrc * 8;
            __builtin_amdgcn_global_load_lds((gv_t*)gp, (lv_t*)(xs + chunk * 512 + ln * 8), 16, 0, 0);
        }
        // stage Wt tile (rows = output cols)
#pragma unroll
        for (int i = 0; i < 4; ++i) {
            const int chunk = wv * 4 + i;
            const int row = chunk * 8 + (ln >> 3);
            const int gsrc = (ln & 7) ^ (row & 7);
            const unsigned short* gp = Wt + (size_t)(col0 + row) * K + k0 + gsrc * 8;
            __builtin_amdgcn_global_load_lds((gv_t*)gp, (lv_t*)(wsx + chunk * 512 + ln * 8), 16, 0, 0);
        }
        __syncthreads();

#pragma unroll
        for (int kk = 0; kk < 2; ++kk) {
            bf16x8 a[4], b[4];
            const int g = kk * 4 + (ln >> 4);
#pragma unroll
            for (int m = 0; m < 4; ++m) {
                const int row = wr2 * 64 + m * 16 + (ln & 15);
                const int s = g ^ (row & 7);
                a[m] = *(const bf16x8*)&xs[row * 64 + s * 8];
            }
#pragma unroll
            for (int n = 0; n < 4; ++n) {
                const int row = wc2 * 64 + n * 16 + (ln & 15);
                const int s = g ^ (row & 7);
                b[n] = *(const bf16x8*)&wsx[row * 64 + s * 8];
            }
#pragma unroll
            for (int m = 0; m < 4; ++m)
#pragma unroll
                for (int n = 0; n < 4; ++n)
                    acc[m][n] = __builtin_amdgcn_mfma_f32_16x16x32_bf16(a[m], b[n], acc[m][n], 0, 0, 0);
        }
        __syncthreads();
    }

    // epilogue: C/D map col=lane&15, row=4*(lane>>4)+q
    float bj[4];
#pragma unroll
    for (int n = 0; n < 4; ++n)
        bj[n] = BIAS ? bias[col0 + wc2 * 64 + n * 16 + (ln & 15)] : 0.f;

#pragma unroll
    for (int m = 0; m < 4; ++m) {
        const long rbase = row0 + wr2 * 64 + m * 16 + 4 * (ln >> 4);
#pragma unroll
        for (int n = 0; n < 4; ++n) {
            const int col = col0 + wc2 * 64 + n * 16 + (ln & 15);
#pragma unroll
            for (int q = 0; q < 4; ++q) {
                const long r = rbase + q;
                if (r >= M) continue;
                const float v = acc[m][n][q] + bj[n];
                if (OUTF32)  Yf[r * HID + col] = v;
                if (OUTBF16) Yb[r * HID + col] = f2b(v);
            }
        }
    }
}

// ======================= CSR build (per launch) =======================
__global__ void hist_dst(const int* __restrict__ dst, int* __restrict__ deg) {
    int i = blockIdx.x * 256 + threadIdx.x;
    if (i < N_EDGES) atomicAdd(&deg[dst[i]], 1);
}

__global__ __launch_bounds__(1024) void scan_block(const int* __restrict__ deg,
                                                   int* __restrict__ sexc,
                                                   int* __restrict__ bsum) {
    int t = threadIdx.x, gid = blockIdx.x * 1024 + t;
    int v = (gid < N_NODES) ? deg[gid] : 0;
    int lane = t & 63, wv = t >> 6;
    int x = v;
#pragma unroll
    for (int o = 1; o < 64; o <<= 1) {
        int y = __shfl_up(x, o);
        if (lane >= o) x += y;
    }
    __shared__ int wsum[16];
    if (lane == 63) wsum[wv] = x;
    __syncthreads();
    if (t == 0) {
        int a = 0;
#pragma unroll
        for (int i = 0; i < 16; ++i) { int tt = wsum[i]; wsum[i] = a; a += tt; }
        bsum[blockIdx.x] = a;
    }
    __syncthreads();
    sexc[gid] = (x - v) + wsum[wv];
}

__global__ __launch_bounds__(128) void scan_partials(int* __restrict__ bsum,
                                                     int* __restrict__ offsets) {
    __shared__ int s[128];
    int t = threadIdx.x;
    int v = (t < NB) ? bsum[t] : 0;
    s[t] = v;
    __syncthreads();
    for (int o = 1; o < 128; o <<= 1) {
        int y = (t >= o) ? s[t - o] : 0;
        __syncthreads();
        s[t] += y;
        __syncthreads();
    }
    if (t < NB) bsum[t] = s[t] - v;
    if (t == 127) offsets[N_NODES] = s[127];
}

__global__ __launch_bounds__(1024) void scan_add(const int* __restrict__ sexc,
                                                 const int* __restrict__ bsum,
                                                 int* __restrict__ offsets) {
    int gid = blockIdx.x * 1024 + threadIdx.x;
    if (gid < N_NODES) offsets[gid] = sexc[gid] + bsum[blockIdx.x];
}

__global__ void csr_fill(const int* __restrict__ src, const int* __restrict__ dst,
                         const int* __restrict__ offsets, int* __restrict__ cnt,
                         int* __restrict__ csrc) {
    int i = blockIdx.x * 256 + threadIdx.x;
    if (i < N_EDGES) {
        int d = dst[i];
        int slot = offsets[d] + atomicAdd(&cnt[d], 1);
        csrc[slot] = src[i];
    }
}

// ===================== per-layer small kernels =====================
// el = z @ al, er = z @ ar. One wave per node; z is bf16.
__global__ void node_dots(const unsigned short* __restrict__ z,
                          const float* __restrict__ al,
                          const float* __restrict__ ar,
                          float* __restrict__ el, float* __restrict__ er) {
    int n = blockIdx.x * 4 + (threadIdx.x >> 6);
    int lane = threadIdx.x & 63;
    ushort4 zz = ((const ushort4*)(z + (size_t)n * HID))[lane];
    float4 a = ((const float4*)al)[lane];
    float4 b = ((const float4*)ar)[lane];
    float z0 = b2f(zz.x), z1 = b2f(zz.y), z2 = b2f(zz.z), z3 = b2f(zz.w);
    float pl = z0 * a.x + z1 * a.y + z2 * a.z + z3 * a.w;
    float pr = z0 * b.x + z1 * b.y + z2 * b.z + z3 * b.w;
#pragma unroll
    for (int off = 32; off > 0; off >>= 1) {
        pl += __shfl_down(pl, off);
        pr += __shfl_down(pr, off);
    }
    if (lane == 0) { el[n] = pl; er[n] = pr; }
}

// One wave per dst node: segment softmax + alpha-weighted z gather +
// residual + ReLU. Writes A (f32, residual state) and Ab (bf16, next GEMM input).
__global__ __launch_bounds__(256) void fused_attn(const int* __restrict__ offs,
                                                  const int* __restrict__ csrc,
                                                  const float* __restrict__ el,
                                                  const float* __restrict__ er,
                                                  const unsigned short* __restrict__ z,
                                                  float* __restrict__ A,
                                                  unsigned short* __restrict__ Ab) {
    const int n = blockIdx.x * 4 + (threadIdx.x >> 6);
    const int lane = threadIdx.x & 63;
    const int beg = offs[n], end = offs[n + 1];
    const float ern = er[n];

    float m = -3.4e38f;
    for (int c = beg + lane; c < end; c += 64) {
        float v = el[csrc[c]] + ern;
        v = (v >= 0.f) ? v : NEG_SLOPE * v;
        m = fmaxf(m, v);
    }
#pragma unroll
    for (int o = 32; o > 0; o >>= 1) m = fmaxf(m, __shfl_xor(m, o));

    float s = 0.f;
    for (int c = beg + lane; c < end; c += 64) {
        float v = el[csrc[c]] + ern;
        v = (v >= 0.f) ? v : NEG_SLOPE * v;
        s += __expf(v - m);
    }
#pragma unroll
    for (int o = 32; o > 0; o >>= 1) s += __shfl_xor(s, o);
    const float inv = 1.f / (s + EPS);

    float4 acc = make_float4(0.f, 0.f, 0.f, 0.f);
    for (int c = beg; c < end; ++c) {
        int sc = csrc[c];                       // wave-uniform -> broadcast
        float v = el[sc] + ern;
        v = (v >= 0.f) ? v : NEG_SLOPE * v;
        float alpha = __expf(v - m) * inv;
        ushort4 zz = ((const ushort4*)(z + (size_t)sc * HID))[lane];
        acc.x = fmaf(alpha, b2f(zz.x), acc.x);
        acc.y = fmaf(alpha, b2f(zz.y), acc.y);
        acc.z = fmaf(alpha, b2f(zz.z), acc.z);
        acc.w = fmaf(alpha, b2f(zz.w), acc.w);
    }

    float4* Ap = (float4*)(A + (size_t)n * HID);
    float4 h4 = Ap[lane];
    h4.x = fmaxf(h4.x + acc.x, 0.f);
    h4.y = fmaxf(h4.y + acc.y, 0.f);
    h4.z = fmaxf(h4.z + acc.z, 0.f);
    h4.w = fmaxf(h4.w + acc.w, 0.f);
    Ap[lane] = h4;
    ushort4 ob;
    ob.x = f2b(h4.x); ob.y = f2b(h4.y); ob.z = f2b(h4.z); ob.w = f2b(h4.w);
    ((ushort4*)(Ab + (size_t)n * HID))[lane] = ob;
}

// g[graph_ids[n], :] += h[n, :]
__global__ void pool_kernel(const float* __restrict__ h,
                            const int* __restrict__ gid,
                            float* __restrict__ g) {
    int n = blockIdx.x, t = threadIdx.x;
    atomicAdd(&g[gid[n] * HID + t], h[n * HID + t]);
}

// fused MLP: relu(g@w1+b1) -> relu(@w2+b2) -> @w3+b3
__global__ void mlp_kernel(const float* __restrict__ g,
                           const float* __restrict__ w1, const float* __restrict__ b1,
                           const float* __restrict__ w2, const float* __restrict__ b2,
                           const float* __restrict__ w3, const float* __restrict__ b3,
                           float* __restrict__ out) {
    int gi = blockIdx.x, t = threadIdx.x;
    __shared__ float x[HID];
    __shared__ float y1[HID / 2];
    __shared__ float y2[HID / 4];
    x[t] = g[gi * HID + t];
    __syncthreads();
    if (t < HID / 2) {
        float a = b1[t];
#pragma unroll 8
        for (int k = 0; k < HID; ++k) a += x[k] * w1[k * (HID / 2) + t];
        y1[t] = fmaxf(a, 0.f);
    }
    __syncthreads();
    if (t < HID / 4) {
        float a = b2[t];
#pragma unroll 8
        for (int k = 0; k < HID / 2; ++k) a += y1[k] * w2[k * (HID / 4) + t];
        y2[t] = fmaxf(a, 0.f);
    }
    __syncthreads();
    if (t < 64) {
        float p = y2[t] * w3[t];
#pragma unroll
        for (int off = 32; off > 0; off >>= 1) p += __shfl_down(p, off);
        if (t == 0) out[gi] = p + b3[0];
    }
}

extern "C" void kernel_launch(void* const* d_in, const int* in_sizes, int n_in,
                              void* d_out, int out_size, void* d_ws, size_t ws_size,
                              hipStream_t stream) {
    const float* node_feats = (const float*)d_in[0];
    const int*   src        = (const int*)d_in[1];
    const int*   dst        = (const int*)d_in[2];
    const int*   graph_ids  = (const int*)d_in[3];
    const float* w_embed    = (const float*)d_in[4];
    const float* b_embed    = (const float*)d_in[5];
    const float* gat_W      = (const float*)d_in[6];
    const float* gat_al     = (const float*)d_in[7];
    const float* gat_ar     = (const float*)d_in[8];
    const float* w1         = (const float*)d_in[9];
    const float* b1         = (const float*)d_in[10];
    const float* w2         = (const float*)d_in[11];
    const float* b2         = (const float*)d_in[12];
    const float* w3         = (const float*)d_in[13];
    const float* b3         = (const float*)d_in[14];
    float* out = (float*)d_out;

    char* ws = (char*)d_ws;
    size_t off = 0;
    auto alloc = [&](size_t bytes) { char* p = ws + off; off += (bytes + 255) & ~size_t(255); return p; };
    float*          A       = (float*)alloc((size_t)N_NODES * HID * 4);          // h (f32)
    unsigned short* Ab      = (unsigned short*)alloc((size_t)N_NODES * HID * 2); // h (bf16)
    unsigned short* Zb      = (unsigned short*)alloc((size_t)N_NODES * HID * 2); // z (bf16); aliases nfb
    unsigned short* Wt      = (unsigned short*)alloc((size_t)HID * HID * 2);     // W^T bf16
    float*          el      = (float*)alloc((size_t)N_NODES * 4);
    float*          er      = (float*)alloc((size_t)N_NODES * 4);
    int*            deg     = (int*)alloc((size_t)N_NODES * 4);
    int*            cnt     = (int*)alloc((size_t)N_NODES * 4);
    int*            sexc    = (int*)alloc((size_t)NB * 1024 * 4);
    int*            bsum    = (int*)alloc(128 * 4);
    int*            offsets = (int*)alloc((size_t)(N_NODES + 1) * 4);
    int*            csrc    = (int*)alloc((size_t)N_EDGES * 4);
    float*          g       = (float*)alloc((size_t)N_GRAPHS * HID * 4);
    unsigned short* nfb     = Zb;  // node_feats bf16, dead before Zb first written

    // ---- CSR build (graph static across layers) ----
    hipMemsetAsync(deg, 0, (size_t)N_NODES * 4, stream);
    hipMemsetAsync(cnt, 0, (size_t)N_NODES * 4, stream);
    hist_dst<<<(N_EDGES + 255) / 256, 256, 0, stream>>>(dst, deg);
    scan_block<<<NB, 1024, 0, stream>>>(deg, sexc, bsum);
    scan_partials<<<1, 128, 0, stream>>>(bsum, offsets);
    scan_add<<<NB, 1024, 0, stream>>>(sexc, bsum, offsets);
    csr_fill<<<(N_EDGES + 255) / 256, 256, 0, stream>>>(src, dst, offsets, cnt, csrc);

    dim3 ggrid((N_NODES + 127) / 128, HID / 128);

    // ---- embed: h = nf @ w_embed + b (MFMA, bf16 inputs, f32+bf16 out) ----
    convert_f32_bf16<<<(N_NODES * NODE_DIM / 4 + 255) / 256, 256, 0, stream>>>(node_feats, nfb, N_NODES * NODE_DIM / 4);
    transpose_bf16<<<dim3(NODE_DIM / 32, HID / 32), 256, 0, stream>>>(w_embed, Wt, NODE_DIM);
    gemm_mfma<NODE_DIM, true, true, true><<<ggrid, 256, 0, stream>>>(nfb, Wt, b_embed, A, Ab, N_NODES);

    for (int l = 0; l < N_GAT; ++l) {
        const float* W  = gat_W  + (size_t)l * HID * HID;
        const float* al = gat_al + (size_t)l * HID;
        const float* ar = gat_ar + (size_t)l * HID;

        transpose_bf16<<<dim3(HID / 32, HID / 32), 256, 0, stream>>>(W, Wt, HID);
        gemm_mfma<HID, false, false, true><<<ggrid, 256, 0, stream>>>(Ab, Wt, nullptr, nullptr, Zb, N_NODES);
        node_dots<<<N_NODES / 4, 256, 0, stream>>>(Zb, al, ar, el, er);
        fused_attn<<<N_NODES / 4, 256, 0, stream>>>(offsets, csrc, el, er, Zb, A, Ab);
    }

    hipMemsetAsync(g, 0, (size_t)N_GRAPHS * HID * 4, stream);
    pool_kernel<<<N_NODES, HID, 0, stream>>>(A, graph_ids, g);

    mlp_kernel<<<N_GRAPHS, HID, 0, stream>>>(g, w1, b1, w2, b2, w3, b3, out);
}

// Round 6
// 614.194 us; speedup vs baseline: 7.0979x; 1.0549x over previous
//
#include <hip/hip_runtime.h>
#include <hip/hip_bf16.h>

#define N_NODES 100000
#define N_EDGES 200000
#define N_GRAPHS 4096
#define NODE_DIM 64
#define HID 256
#define N_GAT 4
#define NEG_SLOPE 0.2f
#define EPS 1e-9f
#define NB 98  // ceil(N_NODES/1024)

typedef const __attribute__((address_space(1))) void gv_t;
typedef __attribute__((address_space(3))) void lv_t;
typedef __attribute__((ext_vector_type(8))) short bf16x8;
typedef __attribute__((ext_vector_type(4))) float f32x4;

__device__ __forceinline__ float b2f(unsigned short u) {
    return __uint_as_float(((unsigned)u) << 16);
}
__device__ __forceinline__ unsigned short f2b(float f) {   // RNE
    unsigned u = __float_as_uint(f);
    return (unsigned short)((u + 0x7fffu + ((u >> 16) & 1u)) >> 16);
}

// ==================== converters ====================
__global__ void convert_f32_bf16(const float* __restrict__ src,
                                 unsigned short* __restrict__ dst, int n4) {
    int i = blockIdx.x * 256 + threadIdx.x;
    if (i >= n4) return;
    float4 v = ((const float4*)src)[i];
    ushort4 o;
    o.x = f2b(v.x); o.y = f2b(v.y); o.z = f2b(v.z); o.w = f2b(v.w);
    ((ushort4*)dst)[i] = o;
}

// Wt[c][k] = bf16(W[k][c]);  W is [K][256], Wt is [256][K]
__global__ __launch_bounds__(256) void transpose_bf16(const float* __restrict__ W,
                                                      unsigned short* __restrict__ Wt,
                                                      int K) {
    __shared__ float tile[32][33];
    const int kb = blockIdx.x * 32, cb = blockIdx.y * 32;
    const int tr = threadIdx.x >> 5, tc = threadIdx.x & 31;
#pragma unroll
    for (int i = 0; i < 4; ++i)
        tile[tr + i * 8][tc] = W[(size_t)(kb + tr + i * 8) * HID + cb + tc];
    __syncthreads();
#pragma unroll
    for (int i = 0; i < 4; ++i)
        Wt[(size_t)(cb + tr + i * 8) * K + kb + tc] = f2b(tile[tc][tr + i * 8]);
}

// ==================== MFMA GEMM (+fused attention dots) ====================
// Y[M,256] = X[M,K](bf16) @ Wt[256,K](bf16, pre-transposed) (+bias).
// 128x128 block tile, 4 waves (64x64 each), 4x4 frags of 16x16x32 bf16 MFMA.
// Both LDS tiles [row][KC] with 16B-granule XOR swizzle (g ^= row&7), applied
// on the GLOBAL source address (global_load_lds dest stays linear).
// If DOTS: el[r] += z[r]·al, er[r] += z[r]·ar accumulated from f32 acc
// (el/er must be pre-zeroed; ~4 atomic contributions per row).
template <int K, bool BIAS, bool OUTF32, bool OUTBF16, bool DOTS>
__global__ __launch_bounds__(256) void gemm_mfma(const unsigned short* __restrict__ Xb,
                                                 const unsigned short* __restrict__ Wt,
                                                 const float* __restrict__ bias,
                                                 float* __restrict__ Yf,
                                                 unsigned short* __restrict__ Yb,
                                                 const float* __restrict__ al,
                                                 const float* __restrict__ ar,
                                                 float* __restrict__ el,
                                                 float* __restrict__ er,
                                                 int M) {
    constexpr int KC = 64;
    __shared__ unsigned short xs[128 * KC];   // [row][64] bf16, swizzled granules
    __shared__ unsigned short wsx[128 * KC];  // [col][64] bf16, swizzled granules
    const int t = threadIdx.x, wv = t >> 6, ln = t & 63;
    const int wr2 = wv >> 1, wc2 = wv & 1;    // wave quadrant (2x2)
    const long row0 = (long)blockIdx.x * 128;
    const int  col0 = blockIdx.y * 128;

    f32x4 acc[4][4];
#pragma unroll
    for (int m = 0; m < 4; ++m)
#pragma unroll
        for (int n = 0; n < 4; ++n) acc[m][n] = (f32x4){0.f, 0.f, 0.f, 0.f};

    for (int k0 = 0; k0 < K; k0 += KC) {
        // stage X tile: 16 chunks of 1KB (8 rows each), 4 per wave
#pragma unroll
        for (int i = 0; i < 4; ++i) {
            const int chunk = wv * 4 + i;
            const int row = chunk * 8 + (ln >> 3);
            const int gsrc = (ln & 7) ^ (row & 7);
            long gr = row0 + row; if (gr >= M) gr = M - 1;
            const unsigned short* gp = Xb + gr * K + k0 + gsrc * 8;
            __builtin_amdgcn_global_load_lds((gv_t*)gp, (lv_t*)(xs + chunk * 512 + ln * 8), 16, 0, 0);
        }
        // stage Wt tile (rows = output cols)
#pragma unroll
        for (int i = 0; i < 4; ++i) {
            const int chunk = wv * 4 + i;
            const int row = chunk * 8 + (ln >> 3);
            const int gsrc = (ln & 7) ^ (row & 7);
            const unsigned short* gp = Wt + (size_t)(col0 + row) * K + k0 + gsrc * 8;
            __builtin_amdgcn_global_load_lds((gv_t*)gp, (lv_t*)(wsx + chunk * 512 + ln * 8), 16, 0, 0);
        }
        __syncthreads();

#pragma unroll
        for (int kk = 0; kk < 2; ++kk) {
            bf16x8 a[4], b[4];
            const int g = kk * 4 + (ln >> 4);
#pragma unroll
            for (int m = 0; m < 4; ++m) {
                const int row = wr2 * 64 + m * 16 + (ln & 15);
                const int s = g ^ (row & 7);
                a[m] = *(const bf16x8*)&xs[row * 64 + s * 8];
            }
#pragma unroll
            for (int n = 0; n < 4; ++n) {
                const int row = wc2 * 64 + n * 16 + (ln & 15);
                const int s = g ^ (row & 7);
                b[n] = *(const bf16x8*)&wsx[row * 64 + s * 8];
            }
#pragma unroll
            for (int m = 0; m < 4; ++m)
#pragma unroll
                for (int n = 0; n < 4; ++n)
                    acc[m][n] = __builtin_amdgcn_mfma_f32_16x16x32_bf16(a[m], b[n], acc[m][n], 0, 0, 0);
        }
        __syncthreads();
    }

    // epilogue: C/D map col=lane&15, row=4*(lane>>4)+q
    float bj[4];
#pragma unroll
    for (int n = 0; n < 4; ++n)
        bj[n] = BIAS ? bias[col0 + wc2 * 64 + n * 16 + (ln & 15)] : 0.f;

#pragma unroll
    for (int m = 0; m < 4; ++m) {
        const long rbase = row0 + wr2 * 64 + m * 16 + 4 * (ln >> 4);
#pragma unroll
        for (int n = 0; n < 4; ++n) {
            const int col = col0 + wc2 * 64 + n * 16 + (ln & 15);
#pragma unroll
            for (int q = 0; q < 4; ++q) {
                const long r = rbase + q;
                if (r >= M) continue;
                const float v = acc[m][n][q] + bj[n];
                if (OUTF32)  Yf[r * HID + col] = v;
                if (OUTBF16) Yb[r * HID + col] = f2b(v);
            }
        }
    }

    if (DOTS) {
        float alv[4], arv[4];
#pragma unroll
        for (int n = 0; n < 4; ++n) {
            const int col = col0 + wc2 * 64 + n * 16 + (ln & 15);
            alv[n] = al[col];
            arv[n] = ar[col];
        }
#pragma unroll
        for (int m = 0; m < 4; ++m) {
#pragma unroll
            for (int q = 0; q < 4; ++q) {
                float pl = 0.f, pr = 0.f;
#pragma unroll
                for (int n = 0; n < 4; ++n) {
                    pl = fmaf(acc[m][n][q], alv[n], pl);
                    pr = fmaf(acc[m][n][q], arv[n], pr);
                }
#pragma unroll
                for (int o = 1; o < 16; o <<= 1) {
                    pl += __shfl_xor(pl, o);
                    pr += __shfl_xor(pr, o);
                }
                if ((ln & 15) == 0) {
                    const long r = row0 + wr2 * 64 + m * 16 + 4 * (ln >> 4) + q;
                    if (r < M) {
                        atomicAdd(&el[r], pl);
                        atomicAdd(&er[r], pr);
                    }
                }
            }
        }
    }
}

// ======================= CSR build (per launch) =======================
__global__ void hist_dst(const int* __restrict__ dst, int* __restrict__ deg) {
    int i = blockIdx.x * 256 + threadIdx.x;
    if (i < N_EDGES) atomicAdd(&deg[dst[i]], 1);
}

__global__ __launch_bounds__(1024) void scan_block(const int* __restrict__ deg,
                                                   int* __restrict__ sexc,
                                                   int* __restrict__ bsum) {
    int t = threadIdx.x, gid = blockIdx.x * 1024 + t;
    int v = (gid < N_NODES) ? deg[gid] : 0;
    int lane = t & 63, wv = t >> 6;
    int x = v;
#pragma unroll
    for (int o = 1; o < 64; o <<= 1) {
        int y = __shfl_up(x, o);
        if (lane >= o) x += y;
    }
    __shared__ int wsum[16];
    if (lane == 63) wsum[wv] = x;
    __syncthreads();
    if (t == 0) {
        int a = 0;
#pragma unroll
        for (int i = 0; i < 16; ++i) { int tt = wsum[i]; wsum[i] = a; a += tt; }
        bsum[blockIdx.x] = a;
    }
    __syncthreads();
    sexc[gid] = (x - v) + wsum[wv];
}

__global__ __launch_bounds__(128) void scan_partials(int* __restrict__ bsum,
                                                     int* __restrict__ offsets) {
    __shared__ int s[128];
    int t = threadIdx.x;
    int v = (t < NB) ? bsum[t] : 0;
    s[t] = v;
    __syncthreads();
    for (int o = 1; o < 128; o <<= 1) {
        int y = (t >= o) ? s[t - o] : 0;
        __syncthreads();
        s[t] += y;
        __syncthreads();
    }
    if (t < NB) bsum[t] = s[t] - v;
    if (t == 127) offsets[N_NODES] = s[127];
}

__global__ __launch_bounds__(1024) void scan_add(const int* __restrict__ sexc,
                                                 const int* __restrict__ bsum,
                                                 int* __restrict__ offsets) {
    int gid = blockIdx.x * 1024 + threadIdx.x;
    if (gid < N_NODES) offsets[gid] = sexc[gid] + bsum[blockIdx.x];
}

__global__ void csr_fill(const int* __restrict__ src, const int* __restrict__ dst,
                         const int* __restrict__ offsets, int* __restrict__ cnt,
                         int* __restrict__ csrc) {
    int i = blockIdx.x * 256 + threadIdx.x;
    if (i < N_EDGES) {
        int d = dst[i];
        int slot = offsets[d] + atomicAdd(&cnt[d], 1);
        csrc[slot] = src[i];
    }
}

// goff[g] = lower_bound(graph_ids, g); graph_ids is sorted.
__global__ void graph_offsets(const int* __restrict__ gid, int* __restrict__ goff) {
    int g = blockIdx.x * 256 + threadIdx.x;
    if (g > N_GRAPHS) return;
    int lo = 0, hi = N_NODES;
    while (lo < hi) {
        int mid = (lo + hi) >> 1;
        if (gid[mid] < g) lo = mid + 1; else hi = mid;
    }
    goff[g] = lo;
}

// ===================== per-layer small kernels =====================
// One wave per dst node: segment softmax + alpha-weighted z gather +
// residual + ReLU. Writes A (f32, residual state) and Ab (bf16, next GEMM input).
__global__ __launch_bounds__(256) void fused_attn(const int* __restrict__ offs,
                                                  const int* __restrict__ csrc,
                                                  const float* __restrict__ el,
                                                  const float* __restrict__ er,
                                                  const unsigned short* __restrict__ z,
                                                  float* __restrict__ A,
                                                  unsigned short* __restrict__ Ab) {
    const int n = blockIdx.x * 4 + (threadIdx.x >> 6);
    const int lane = threadIdx.x & 63;
    const int beg = offs[n], end = offs[n + 1];
    const float ern = er[n];

    float m = -3.4e38f;
    for (int c = beg + lane; c < end; c += 64) {
        float v = el[csrc[c]] + ern;
        v = (v >= 0.f) ? v : NEG_SLOPE * v;
        m = fmaxf(m, v);
    }
#pragma unroll
    for (int o = 32; o > 0; o >>= 1) m = fmaxf(m, __shfl_xor(m, o));

    float s = 0.f;
    for (int c = beg + lane; c < end; c += 64) {
        float v = el[csrc[c]] + ern;
        v = (v >= 0.f) ? v : NEG_SLOPE * v;
        s += __expf(v - m);
    }
#pragma unroll
    for (int o = 32; o > 0; o >>= 1) s += __shfl_xor(s, o);
    const float inv = 1.f / (s + EPS);

    float4 acc = make_float4(0.f, 0.f, 0.f, 0.f);
    for (int c = beg; c < end; ++c) {
        int sc = csrc[c];                       // wave-uniform -> broadcast
        float v = el[sc] + ern;
        v = (v >= 0.f) ? v : NEG_SLOPE * v;
        float alpha = __expf(v - m) * inv;
        ushort4 zz = ((const ushort4*)(z + (size_t)sc * HID))[lane];
        acc.x = fmaf(alpha, b2f(zz.x), acc.x);
        acc.y = fmaf(alpha, b2f(zz.y), acc.y);
        acc.z = fmaf(alpha, b2f(zz.z), acc.z);
        acc.w = fmaf(alpha, b2f(zz.w), acc.w);
    }

    float4* Ap = (float4*)(A + (size_t)n * HID);
    float4 h4 = Ap[lane];
    h4.x = fmaxf(h4.x + acc.x, 0.f);
    h4.y = fmaxf(h4.y + acc.y, 0.f);
    h4.z = fmaxf(h4.z + acc.z, 0.f);
    h4.w = fmaxf(h4.w + acc.w, 0.f);
    Ap[lane] = h4;
    ushort4 ob;
    ob.x = f2b(h4.x); ob.y = f2b(h4.y); ob.z = f2b(h4.z); ob.w = f2b(h4.w);
    ((ushort4*)(Ab + (size_t)n * HID))[lane] = ob;
}

// g[gi,:] = sum of h rows in [goff[gi], goff[gi+1]) — sorted segments, no atomics
__global__ __launch_bounds__(256) void pool_seg(const float* __restrict__ h,
                                                const int* __restrict__ goff,
                                                float* __restrict__ g) {
    const int gi = blockIdx.x, t = threadIdx.x;
    const int beg = goff[gi], end = goff[gi + 1];
    float acc = 0.f;
    for (int n = beg; n < end; ++n) acc += h[(size_t)n * HID + t];
    g[(size_t)gi * HID + t] = acc;
}

// fused MLP: relu(g@w1+b1) -> relu(@w2+b2) -> @w3+b3
__global__ void mlp_kernel(const float* __restrict__ g,
                           const float* __restrict__ w1, const float* __restrict__ b1,
                           const float* __restrict__ w2, const float* __restrict__ b2,
                           const float* __restrict__ w3, const float* __restrict__ b3,
                           float* __restrict__ out) {
    int gi = blockIdx.x, t = threadIdx.x;
    __shared__ float x[HID];
    __shared__ float y1[HID / 2];
    __shared__ float y2[HID / 4];
    x[t] = g[gi * HID + t];
    __syncthreads();
    if (t < HID / 2) {
        float a = b1[t];
#pragma unroll 8
        for (int k = 0; k < HID; ++k) a += x[k] * w1[k * (HID / 2) + t];
        y1[t] = fmaxf(a, 0.f);
    }
    __syncthreads();
    if (t < HID / 4) {
        float a = b2[t];
#pragma unroll 8
        for (int k = 0; k < HID / 2; ++k) a += y1[k] * w2[k * (HID / 4) + t];
        y2[t] = fmaxf(a, 0.f);
    }
    __syncthreads();
    if (t < 64) {
        float p = y2[t] * w3[t];
#pragma unroll
        for (int off = 32; off > 0; off >>= 1) p += __shfl_down(p, off);
        if (t == 0) out[gi] = p + b3[0];
    }
}

extern "C" void kernel_launch(void* const* d_in, const int* in_sizes, int n_in,
                              void* d_out, int out_size, void* d_ws, size_t ws_size,
                              hipStream_t stream) {
    const float* node_feats = (const float*)d_in[0];
    const int*   src        = (const int*)d_in[1];
    const int*   dst        = (const int*)d_in[2];
    const int*   graph_ids  = (const int*)d_in[3];
    const float* w_embed    = (const float*)d_in[4];
    const float* b_embed    = (const float*)d_in[5];
    const float* gat_W      = (const float*)d_in[6];
    const float* gat_al     = (const float*)d_in[7];
    const float* gat_ar     = (const float*)d_in[8];
    const float* w1         = (const float*)d_in[9];
    const float* b1         = (const float*)d_in[10];
    const float* w2         = (const float*)d_in[11];
    const float* b2         = (const float*)d_in[12];
    const float* w3         = (const float*)d_in[13];
    const float* b3         = (const float*)d_in[14];
    float* out = (float*)d_out;

    char* ws = (char*)d_ws;
    size_t off = 0;
    auto alloc = [&](size_t bytes) { char* p = ws + off; off += (bytes + 255) & ~size_t(255); return p; };
    float*          A       = (float*)alloc((size_t)N_NODES * HID * 4);          // h (f32)
    unsigned short* Ab      = (unsigned short*)alloc((size_t)N_NODES * HID * 2); // h (bf16)
    unsigned short* Zb      = (unsigned short*)alloc((size_t)N_NODES * HID * 2); // z (bf16); aliases nfb
    unsigned short* Wt      = (unsigned short*)alloc((size_t)HID * HID * 2);     // W^T bf16
    float*          el      = (float*)alloc((size_t)N_NODES * 4);
    float*          er      = (float*)alloc((size_t)N_NODES * 4);
    int*            deg     = (int*)alloc((size_t)N_NODES * 4);
    int*            cnt     = (int*)alloc((size_t)N_NODES * 4);
    int*            sexc    = (int*)alloc((size_t)NB * 1024 * 4);
    int*            bsum    = (int*)alloc(128 * 4);
    int*            offsets = (int*)alloc((size_t)(N_NODES + 1) * 4);
    int*            csrc    = (int*)alloc((size_t)N_EDGES * 4);
    int*            goff    = (int*)alloc((size_t)(N_GRAPHS + 1) * 4);
    float*          g       = (float*)alloc((size_t)N_GRAPHS * HID * 4);
    unsigned short* nfb     = Zb;  // node_feats bf16, dead before Zb first written

    // ---- CSR build (graph static across layers) + graph offsets ----
    hipMemsetAsync(deg, 0, (size_t)N_NODES * 4, stream);
    hipMemsetAsync(cnt, 0, (size_t)N_NODES * 4, stream);
    hist_dst<<<(N_EDGES + 255) / 256, 256, 0, stream>>>(dst, deg);
    scan_block<<<NB, 1024, 0, stream>>>(deg, sexc, bsum);
    scan_partials<<<1, 128, 0, stream>>>(bsum, offsets);
    scan_add<<<NB, 1024, 0, stream>>>(sexc, bsum, offsets);
    csr_fill<<<(N_EDGES + 255) / 256, 256, 0, stream>>>(src, dst, offsets, cnt, csrc);
    graph_offsets<<<(N_GRAPHS + 256) / 256, 256, 0, stream>>>(graph_ids, goff);

    dim3 ggrid((N_NODES + 127) / 128, HID / 128);

    // ---- embed: h = nf @ w_embed + b (MFMA, bf16 inputs, f32+bf16 out) ----
    convert_f32_bf16<<<(N_NODES * NODE_DIM / 4 + 255) / 256, 256, 0, stream>>>(node_feats, nfb, N_NODES * NODE_DIM / 4);
    transpose_bf16<<<dim3(NODE_DIM / 32, HID / 32), 256, 0, stream>>>(w_embed, Wt, NODE_DIM);
    gemm_mfma<NODE_DIM, true, true, true, false><<<ggrid, 256, 0, stream>>>(
        nfb, Wt, b_embed, A, Ab, nullptr, nullptr, nullptr, nullptr, N_NODES);

    for (int l = 0; l < N_GAT; ++l) {
        const float* W  = gat_W  + (size_t)l * HID * HID;
        const float* al = gat_al + (size_t)l * HID;
        const float* ar = gat_ar + (size_t)l * HID;

        transpose_bf16<<<dim3(HID / 32, HID / 32), 256, 0, stream>>>(W, Wt, HID);
        hipMemsetAsync(el, 0, (size_t)N_NODES * 4, stream);
        hipMemsetAsync(er, 0, (size_t)N_NODES * 4, stream);
        gemm_mfma<HID, false, false, true, true><<<ggrid, 256, 0, stream>>>(
            Ab, Wt, nullptr, nullptr, Zb, al, ar, el, er, N_NODES);
        fused_attn<<<N_NODES / 4, 256, 0, stream>>>(offsets, csrc, el, er, Zb, A, Ab);
    }

    pool_seg<<<N_GRAPHS, 256, 0, stream>>>(A, goff, g);
    mlp_kernel<<<N_GRAPHS, HID, 0, stream>>>(g, w1, b1, w2, b2, w3, b3, out);
}

// Round 7
// 560.368 us; speedup vs baseline: 7.7797x; 1.0961x over previous
//
#include <hip/hip_runtime.h>
#include <hip/hip_bf16.h>

#define N_NODES 100000
#define N_EDGES 200000
#define N_GRAPHS 4096
#define NODE_DIM 64
#define HID 256
#define N_GAT 4
#define NEG_SLOPE 0.2f
#define EPS 1e-9f
#define NB 98  // ceil(N_NODES/1024)

typedef const __attribute__((address_space(1))) void gv_t;
typedef __attribute__((address_space(3))) void lv_t;
typedef __attribute__((ext_vector_type(8))) short bf16x8;
typedef __attribute__((ext_vector_type(4))) float f32x4;

__device__ __forceinline__ float b2f(unsigned short u) {
    return __uint_as_float(((unsigned)u) << 16);
}
__device__ __forceinline__ unsigned short f2b(float f) {   // RNE
    unsigned u = __float_as_uint(f);
    return (unsigned short)((u + 0x7fffu + ((u >> 16) & 1u)) >> 16);
}

// ==================== converters ====================
__global__ void convert_f32_bf16(const float* __restrict__ src,
                                 unsigned short* __restrict__ dst, int n4) {
    int i = blockIdx.x * 256 + threadIdx.x;
    if (i >= n4) return;
    float4 v = ((const float4*)src)[i];
    ushort4 o;
    o.x = f2b(v.x); o.y = f2b(v.y); o.z = f2b(v.z); o.w = f2b(v.w);
    ((ushort4*)dst)[i] = o;
}

// Wt[c][k] = bf16(W[k][c]);  W is [K][256], Wt is [256][K]
__global__ __launch_bounds__(256) void transpose_bf16(const float* __restrict__ W,
                                                      unsigned short* __restrict__ Wt,
                                                      int K) {
    __shared__ float tile[32][33];
    const int kb = blockIdx.x * 32, cb = blockIdx.y * 32;
    const int tr = threadIdx.x >> 5, tc = threadIdx.x & 31;
#pragma unroll
    for (int i = 0; i < 4; ++i)
        tile[tr + i * 8][tc] = W[(size_t)(kb + tr + i * 8) * HID + cb + tc];
    __syncthreads();
#pragma unroll
    for (int i = 0; i < 4; ++i)
        Wt[(size_t)(cb + tr + i * 8) * K + kb + tc] = f2b(tile[tc][tr + i * 8]);
}

// ==================== MFMA GEMM (+fused attention dots) ====================
// Y[M,256] = X[M,K](bf16) @ Wt[256,K](bf16, pre-transposed) (+bias).
// 128x128 block tile, 4 waves (64x64 each), 4x4 frags of 16x16x32 bf16 MFMA.
// Both LDS tiles [row][KC] with 16B-granule XOR swizzle (g ^= row&7), applied
// on the GLOBAL source address (global_load_lds dest stays linear).
// If DOTS: el[r] += z[r]·al, er[r] += z[r]·ar accumulated from f32 acc
// (el/er must be pre-zeroed; ~4 atomic contributions per row).
template <int K, bool BIAS, bool DOTS>
__global__ __launch_bounds__(256) void gemm_mfma(const unsigned short* __restrict__ Xb,
                                                 const unsigned short* __restrict__ Wt,
                                                 const float* __restrict__ bias,
                                                 unsigned short* __restrict__ Yb,
                                                 const float* __restrict__ al,
                                                 const float* __restrict__ ar,
                                                 float* __restrict__ el,
                                                 float* __restrict__ er,
                                                 int M) {
    constexpr int KC = 64;
    __shared__ unsigned short xs[128 * KC];   // [row][64] bf16, swizzled granules
    __shared__ unsigned short wsx[128 * KC];  // [col][64] bf16, swizzled granules
    const int t = threadIdx.x, wv = t >> 6, ln = t & 63;
    const int wr2 = wv >> 1, wc2 = wv & 1;    // wave quadrant (2x2)
    const long row0 = (long)blockIdx.x * 128;
    const int  col0 = blockIdx.y * 128;

    f32x4 acc[4][4];
#pragma unroll
    for (int m = 0; m < 4; ++m)
#pragma unroll
        for (int n = 0; n < 4; ++n) acc[m][n] = (f32x4){0.f, 0.f, 0.f, 0.f};

    for (int k0 = 0; k0 < K; k0 += KC) {
        // stage X tile: 16 chunks of 1KB (8 rows each), 4 per wave
#pragma unroll
        for (int i = 0; i < 4; ++i) {
            const int chunk = wv * 4 + i;
            const int row = chunk * 8 + (ln >> 3);
            const int gsrc = (ln & 7) ^ (row & 7);
            long gr = row0 + row; if (gr >= M) gr = M - 1;
            const unsigned short* gp = Xb + gr * K + k0 + gsrc * 8;
            __builtin_amdgcn_global_load_lds((gv_t*)gp, (lv_t*)(xs + chunk * 512 + ln * 8), 16, 0, 0);
        }
        // stage Wt tile (rows = output cols)
#pragma unroll
        for (int i = 0; i < 4; ++i) {
            const int chunk = wv * 4 + i;
            const int row = chunk * 8 + (ln >> 3);
            const int gsrc = (ln & 7) ^ (row & 7);
            const unsigned short* gp = Wt + (size_t)(col0 + row) * K + k0 + gsrc * 8;
            __builtin_amdgcn_global_load_lds((gv_t*)gp, (lv_t*)(wsx + chunk * 512 + ln * 8), 16, 0, 0);
        }
        __syncthreads();

#pragma unroll
        for (int kk = 0; kk < 2; ++kk) {
            bf16x8 a[4], b[4];
            const int g = kk * 4 + (ln >> 4);
#pragma unroll
            for (int m = 0; m < 4; ++m) {
                const int row = wr2 * 64 + m * 16 + (ln & 15);
                const int s = g ^ (row & 7);
                a[m] = *(const bf16x8*)&xs[row * 64 + s * 8];
            }
#pragma unroll
            for (int n = 0; n < 4; ++n) {
                const int row = wc2 * 64 + n * 16 + (ln & 15);
                const int s = g ^ (row & 7);
                b[n] = *(const bf16x8*)&wsx[row * 64 + s * 8];
            }
#pragma unroll
            for (int m = 0; m < 4; ++m)
#pragma unroll
                for (int n = 0; n < 4; ++n)
                    acc[m][n] = __builtin_amdgcn_mfma_f32_16x16x32_bf16(a[m], b[n], acc[m][n], 0, 0, 0);
        }
        __syncthreads();
    }

    // epilogue: C/D map col=lane&15, row=4*(lane>>4)+q
    float bj[4];
#pragma unroll
    for (int n = 0; n < 4; ++n)
        bj[n] = BIAS ? bias[col0 + wc2 * 64 + n * 16 + (ln & 15)] : 0.f;

#pragma unroll
    for (int m = 0; m < 4; ++m) {
        const long rbase = row0 + wr2 * 64 + m * 16 + 4 * (ln >> 4);
#pragma unroll
        for (int n = 0; n < 4; ++n) {
            const int col = col0 + wc2 * 64 + n * 16 + (ln & 15);
#pragma unroll
            for (int q = 0; q < 4; ++q) {
                const long r = rbase + q;
                if (r >= M) continue;
                Yb[r * HID + col] = f2b(acc[m][n][q] + bj[n]);
            }
        }
    }

    if (DOTS) {
        float alv[4], arv[4];
#pragma unroll
        for (int n = 0; n < 4; ++n) {
            const int col = col0 + wc2 * 64 + n * 16 + (ln & 15);
            alv[n] = al[col];
            arv[n] = ar[col];
        }
#pragma unroll
        for (int m = 0; m < 4; ++m) {
#pragma unroll
            for (int q = 0; q < 4; ++q) {
                float pl = 0.f, pr = 0.f;
#pragma unroll
                for (int n = 0; n < 4; ++n) {
                    pl = fmaf(acc[m][n][q], alv[n], pl);
                    pr = fmaf(acc[m][n][q], arv[n], pr);
                }
#pragma unroll
                for (int o = 1; o < 16; o <<= 1) {
                    pl += __shfl_xor(pl, o);
                    pr += __shfl_xor(pr, o);
                }
                if ((ln & 15) == 0) {
                    const long r = row0 + wr2 * 64 + m * 16 + 4 * (ln >> 4) + q;
                    if (r < M) {
                        atomicAdd(&el[r], pl);
                        atomicAdd(&er[r], pr);
                    }
                }
            }
        }
    }
}

// ======================= CSR build (per launch) =======================
__global__ void hist_dst(const int* __restrict__ dst, int* __restrict__ deg) {
    int i = blockIdx.x * 256 + threadIdx.x;
    if (i < N_EDGES) atomicAdd(&deg[dst[i]], 1);
}

__global__ __launch_bounds__(1024) void scan_block(const int* __restrict__ deg,
                                                   int* __restrict__ sexc,
                                                   int* __restrict__ bsum) {
    int t = threadIdx.x, gid = blockIdx.x * 1024 + t;
    int v = (gid < N_NODES) ? deg[gid] : 0;
    int lane = t & 63, wv = t >> 6;
    int x = v;
#pragma unroll
    for (int o = 1; o < 64; o <<= 1) {
        int y = __shfl_up(x, o);
        if (lane >= o) x += y;
    }
    __shared__ int wsum[16];
    if (lane == 63) wsum[wv] = x;
    __syncthreads();
    if (t == 0) {
        int a = 0;
#pragma unroll
        for (int i = 0; i < 16; ++i) { int tt = wsum[i]; wsum[i] = a; a += tt; }
        bsum[blockIdx.x] = a;
    }
    __syncthreads();
    sexc[gid] = (x - v) + wsum[wv];
}

__global__ __launch_bounds__(128) void scan_partials(int* __restrict__ bsum,
                                                     int* __restrict__ offsets) {
    __shared__ int s[128];
    int t = threadIdx.x;
    int v = (t < NB) ? bsum[t] : 0;
    s[t] = v;
    __syncthreads();
    for (int o = 1; o < 128; o <<= 1) {
        int y = (t >= o) ? s[t - o] : 0;
        __syncthreads();
        s[t] += y;
        __syncthreads();
    }
    if (t < NB) bsum[t] = s[t] - v;
    if (t == 127) offsets[N_NODES] = s[127];
}

__global__ __launch_bounds__(1024) void scan_add(const int* __restrict__ sexc,
                                                 const int* __restrict__ bsum,
                                                 int* __restrict__ offsets) {
    int gid = blockIdx.x * 1024 + threadIdx.x;
    if (gid < N_NODES) offsets[gid] = sexc[gid] + bsum[blockIdx.x];
}

__global__ void csr_fill(const int* __restrict__ src, const int* __restrict__ dst,
                         const int* __restrict__ offsets, int* __restrict__ cnt,
                         int* __restrict__ csrc) {
    int i = blockIdx.x * 256 + threadIdx.x;
    if (i < N_EDGES) {
        int d = dst[i];
        int slot = offsets[d] + atomicAdd(&cnt[d], 1);
        csrc[slot] = src[i];
    }
}

// goff[g] = lower_bound(graph_ids, g); graph_ids is sorted.
__global__ void graph_offsets(const int* __restrict__ gid, int* __restrict__ goff) {
    int g = blockIdx.x * 256 + threadIdx.x;
    if (g > N_GRAPHS) return;
    int lo = 0, hi = N_NODES;
    while (lo < hi) {
        int mid = (lo + hi) >> 1;
        if (gid[mid] < g) lo = mid + 1; else hi = mid;
    }
    goff[g] = lo;
}

// ===================== per-layer small kernels =====================
// One wave per dst node: segment softmax + alpha-weighted z gather +
// residual + ReLU. h lives ONLY in bf16 (Ab): read-modify-write in f32 regs.
__global__ __launch_bounds__(256) void fused_attn(const int* __restrict__ offs,
                                                  const int* __restrict__ csrc,
                                                  const float* __restrict__ el,
                                                  const float* __restrict__ er,
                                                  const unsigned short* __restrict__ z,
                                                  unsigned short* __restrict__ Ab) {
    const int n = blockIdx.x * 4 + (threadIdx.x >> 6);
    const int lane = threadIdx.x & 63;
    const int beg = offs[n], end = offs[n + 1];
    const float ern = er[n];

    float m = -3.4e38f;
    for (int c = beg + lane; c < end; c += 64) {
        float v = el[csrc[c]] + ern;
        v = (v >= 0.f) ? v : NEG_SLOPE * v;
        m = fmaxf(m, v);
    }
#pragma unroll
    for (int o = 32; o > 0; o >>= 1) m = fmaxf(m, __shfl_xor(m, o));

    float s = 0.f;
    for (int c = beg + lane; c < end; c += 64) {
        float v = el[csrc[c]] + ern;
        v = (v >= 0.f) ? v : NEG_SLOPE * v;
        s += __expf(v - m);
    }
#pragma unroll
    for (int o = 32; o > 0; o >>= 1) s += __shfl_xor(s, o);
    const float inv = 1.f / (s + EPS);

    float4 acc = make_float4(0.f, 0.f, 0.f, 0.f);
    for (int c = beg; c < end; ++c) {
        int sc = csrc[c];                       // wave-uniform -> broadcast
        float v = el[sc] + ern;
        v = (v >= 0.f) ? v : NEG_SLOPE * v;
        float alpha = __expf(v - m) * inv;
        ushort4 zz = ((const ushort4*)(z + (size_t)sc * HID))[lane];
        acc.x = fmaf(alpha, b2f(zz.x), acc.x);
        acc.y = fmaf(alpha, b2f(zz.y), acc.y);
        acc.z = fmaf(alpha, b2f(zz.z), acc.z);
        acc.w = fmaf(alpha, b2f(zz.w), acc.w);
    }

    ushort4* Ap = (ushort4*)(Ab + (size_t)n * HID);
    ushort4 hh = Ap[lane];
    ushort4 ob;
    ob.x = f2b(fmaxf(b2f(hh.x) + acc.x, 0.f));
    ob.y = f2b(fmaxf(b2f(hh.y) + acc.y, 0.f));
    ob.z = f2b(fmaxf(b2f(hh.z) + acc.z, 0.f));
    ob.w = f2b(fmaxf(b2f(hh.w) + acc.w, 0.f));
    Ap[lane] = ob;
}

// g[gi,:] = sum of bf16 h rows in [goff[gi], goff[gi+1]) — sorted, no atomics
__global__ __launch_bounds__(256) void pool_seg(const unsigned short* __restrict__ h,
                                                const int* __restrict__ goff,
                                                float* __restrict__ g) {
    const int gi = blockIdx.x, t = threadIdx.x;
    const int beg = goff[gi], end = goff[gi + 1];
    float acc = 0.f;
    for (int n = beg; n < end; ++n) acc += b2f(h[(size_t)n * HID + t]);
    g[(size_t)gi * HID + t] = acc;
}

// fused MLP: relu(g@w1+b1) -> relu(@w2+b2) -> @w3+b3
__global__ void mlp_kernel(const float* __restrict__ g,
                           const float* __restrict__ w1, const float* __restrict__ b1,
                           const float* __restrict__ w2, const float* __restrict__ b2,
                           const float* __restrict__ w3, const float* __restrict__ b3,
                           float* __restrict__ out) {
    int gi = blockIdx.x, t = threadIdx.x;
    __shared__ float x[HID];
    __shared__ float y1[HID / 2];
    __shared__ float y2[HID / 4];
    x[t] = g[gi * HID + t];
    __syncthreads();
    if (t < HID / 2) {
        float a = b1[t];
#pragma unroll 8
        for (int k = 0; k < HID; ++k) a += x[k] * w1[k * (HID / 2) + t];
        y1[t] = fmaxf(a, 0.f);
    }
    __syncthreads();
    if (t < HID / 4) {
        float a = b2[t];
#pragma unroll 8
        for (int k = 0; k < HID / 2; ++k) a += y1[k] * w2[k * (HID / 4) + t];
        y2[t] = fmaxf(a, 0.f);
    }
    __syncthreads();
    if (t < 64) {
        float p = y2[t] * w3[t];
#pragma unroll
        for (int off = 32; off > 0; off >>= 1) p += __shfl_down(p, off);
        if (t == 0) out[gi] = p + b3[0];
    }
}

extern "C" void kernel_launch(void* const* d_in, const int* in_sizes, int n_in,
                              void* d_out, int out_size, void* d_ws, size_t ws_size,
                              hipStream_t stream) {
    const float* node_feats = (const float*)d_in[0];
    const int*   src        = (const int*)d_in[1];
    const int*   dst        = (const int*)d_in[2];
    const int*   graph_ids  = (const int*)d_in[3];
    const float* w_embed    = (const float*)d_in[4];
    const float* b_embed    = (const float*)d_in[5];
    const float* gat_W      = (const float*)d_in[6];
    const float* gat_al     = (const float*)d_in[7];
    const float* gat_ar     = (const float*)d_in[8];
    const float* w1         = (const float*)d_in[9];
    const float* b1         = (const float*)d_in[10];
    const float* w2         = (const float*)d_in[11];
    const float* b2         = (const float*)d_in[12];
    const float* w3         = (const float*)d_in[13];
    const float* b3         = (const float*)d_in[14];
    float* out = (float*)d_out;

    char* ws = (char*)d_ws;
    size_t off = 0;
    auto alloc = [&](size_t bytes) { char* p = ws + off; off += (bytes + 255) & ~size_t(255); return p; };
    unsigned short* Ab      = (unsigned short*)alloc((size_t)N_NODES * HID * 2); // h (bf16)
    unsigned short* Zb      = (unsigned short*)alloc((size_t)N_NODES * HID * 2); // z (bf16); aliases nfb
    unsigned short* Wt      = (unsigned short*)alloc((size_t)HID * HID * 2);     // W^T bf16
    float*          eler    = (float*)alloc((size_t)2 * N_NODES * 4);            // el | er
    int*            deg     = (int*)alloc((size_t)N_NODES * 4);
    int*            cnt     = (int*)alloc((size_t)N_NODES * 4);
    int*            sexc    = (int*)alloc((size_t)NB * 1024 * 4);
    int*            bsum    = (int*)alloc(128 * 4);
    int*            offsets = (int*)alloc((size_t)(N_NODES + 1) * 4);
    int*            csrc    = (int*)alloc((size_t)N_EDGES * 4);
    int*            goff    = (int*)alloc((size_t)(N_GRAPHS + 1) * 4);
    float*          g       = (float*)alloc((size_t)N_GRAPHS * HID * 4);
    float*          el      = eler;
    float*          er      = eler + N_NODES;
    unsigned short* nfb     = Zb;  // node_feats bf16, dead before Zb first written

    // ---- CSR build (graph static across layers) + graph offsets ----
    hipMemsetAsync(deg, 0, (size_t)N_NODES * 4, stream);
    hipMemsetAsync(cnt, 0, (size_t)N_NODES * 4, stream);
    hist_dst<<<(N_EDGES + 255) / 256, 256, 0, stream>>>(dst, deg);
    scan_block<<<NB, 1024, 0, stream>>>(deg, sexc, bsum);
    scan_partials<<<1, 128, 0, stream>>>(bsum, offsets);
    scan_add<<<NB, 1024, 0, stream>>>(sexc, bsum, offsets);
    csr_fill<<<(N_EDGES + 255) / 256, 256, 0, stream>>>(src, dst, offsets, cnt, csrc);
    graph_offsets<<<(N_GRAPHS + 256) / 256, 256, 0, stream>>>(graph_ids, goff);

    dim3 ggrid((N_NODES + 127) / 128, HID / 128);

    // ---- embed: h = nf @ w_embed + b (MFMA, bf16 in/out) ----
    convert_f32_bf16<<<(N_NODES * NODE_DIM / 4 + 255) / 256, 256, 0, stream>>>(node_feats, nfb, N_NODES * NODE_DIM / 4);
    transpose_bf16<<<dim3(NODE_DIM / 32, HID / 32), 256, 0, stream>>>(w_embed, Wt, NODE_DIM);
    gemm_mfma<NODE_DIM, true, false><<<ggrid, 256, 0, stream>>>(
        nfb, Wt, b_embed, Ab, nullptr, nullptr, nullptr, nullptr, N_NODES);

    for (int l = 0; l < N_GAT; ++l) {
        const float* W  = gat_W  + (size_t)l * HID * HID;
        const float* al = gat_al + (size_t)l * HID;
        const float* ar = gat_ar + (size_t)l * HID;

        transpose_bf16<<<dim3(HID / 32, HID / 32), 256, 0, stream>>>(W, Wt, HID);
        hipMemsetAsync(eler, 0, (size_t)2 * N_NODES * 4, stream);
        gemm_mfma<HID, false, true><<<ggrid, 256, 0, stream>>>(
            Ab, Wt, nullptr, Zb, al, ar, el, er, N_NODES);
        fused_attn<<<N_NODES / 4, 256, 0, stream>>>(offsets, csrc, el, er, Zb, Ab);
    }

    pool_seg<<<N_GRAPHS, 256, 0, stream>>>(Ab, goff, g);
    mlp_kernel<<<N_GRAPHS, HID, 0, stream>>>(g, w1, b1, w2, b2, w3, b3, out);
}

// Round 8
// 522.698 us; speedup vs baseline: 8.3403x; 1.0721x over previous
//
#include <hip/hip_runtime.h>
#include <hip/hip_bf16.h>

#define N_NODES 100000
#define N_EDGES 200000
#define N_GRAPHS 4096
#define NODE_DIM 64
#define HID 256
#define N_GAT 4
#define NEG_SLOPE 0.2f
#define EPS 1e-9f
#define NB 98  // ceil(N_NODES/1024)

typedef const __attribute__((address_space(1))) void gv_t;
typedef __attribute__((address_space(3))) void lv_t;
typedef __attribute__((ext_vector_type(8))) short bf16x8;
typedef __attribute__((ext_vector_type(4))) float f32x4;

__device__ __forceinline__ float b2f(unsigned short u) {
    return __uint_as_float(((unsigned)u) << 16);
}
__device__ __forceinline__ unsigned short f2b(float f) {   // RNE
    unsigned u = __float_as_uint(f);
    return (unsigned short)((u + 0x7fffu + ((u >> 16) & 1u)) >> 16);
}

// ==================== converters ====================
__global__ void convert_f32_bf16(const float* __restrict__ src,
                                 unsigned short* __restrict__ dst, int n4) {
    int i = blockIdx.x * 256 + threadIdx.x;
    if (i >= n4) return;
    float4 v = ((const float4*)src)[i];
    ushort4 o;
    o.x = f2b(v.x); o.y = f2b(v.y); o.z = f2b(v.z); o.w = f2b(v.w);
    ((ushort4*)dst)[i] = o;
}

// Wt[c][k] = bf16(W[k][c]);  W is [K][256], Wt is [256][K]
__global__ __launch_bounds__(256) void transpose_bf16(const float* __restrict__ W,
                                                      unsigned short* __restrict__ Wt,
                                                      int K) {
    __shared__ float tile[32][33];
    const int kb = blockIdx.x * 32, cb = blockIdx.y * 32;
    const int tr = threadIdx.x >> 5, tc = threadIdx.x & 31;
#pragma unroll
    for (int i = 0; i < 4; ++i)
        tile[tr + i * 8][tc] = W[(size_t)(kb + tr + i * 8) * HID + cb + tc];
    __syncthreads();
#pragma unroll
    for (int i = 0; i < 4; ++i)
        Wt[(size_t)(cb + tr + i * 8) * K + kb + tc] = f2b(tile[tc][tr + i * 8]);
}

// ==================== MFMA GEMM (+fused attention dots) ====================
// Y[M,256] = X[M,K](bf16) @ Wt[256,K](bf16, pre-transposed) (+bias).
// 128x128 block tile, 4 waves (64x64 each), 4x4 frags of 16x16x32 bf16 MFMA.
// Both LDS tiles [row][KC] with 16B-granule XOR swizzle (g ^= row&7), applied
// on the GLOBAL source address (global_load_lds dest stays linear).
// If DOTS: el[r] += z[r]·al, er[r] += z[r]·ar accumulated from f32 acc
// (el/er must be pre-zeroed; 2 atomic contributions per row).
template <int K, bool BIAS, bool DOTS>
__global__ __launch_bounds__(256) void gemm_mfma(const unsigned short* __restrict__ Xb,
                                                 const unsigned short* __restrict__ Wt,
                                                 const float* __restrict__ bias,
                                                 unsigned short* __restrict__ Yb,
                                                 const float* __restrict__ al,
                                                 const float* __restrict__ ar,
                                                 float* __restrict__ el,
                                                 float* __restrict__ er,
                                                 int M) {
    constexpr int KC = 64;
    __shared__ unsigned short xs[128 * KC];   // [row][64] bf16, swizzled granules
    __shared__ unsigned short wsx[128 * KC];  // [col][64] bf16, swizzled granules
    const int t = threadIdx.x, wv = t >> 6, ln = t & 63;
    const int wr2 = wv >> 1, wc2 = wv & 1;    // wave quadrant (2x2)
    const long row0 = (long)blockIdx.x * 128;
    const int  col0 = blockIdx.y * 128;

    f32x4 acc[4][4];
#pragma unroll
    for (int m = 0; m < 4; ++m)
#pragma unroll
        for (int n = 0; n < 4; ++n) acc[m][n] = (f32x4){0.f, 0.f, 0.f, 0.f};

    for (int k0 = 0; k0 < K; k0 += KC) {
        // stage X tile: 16 chunks of 1KB (8 rows each), 4 per wave
#pragma unroll
        for (int i = 0; i < 4; ++i) {
            const int chunk = wv * 4 + i;
            const int row = chunk * 8 + (ln >> 3);
            const int gsrc = (ln & 7) ^ (row & 7);
            long gr = row0 + row; if (gr >= M) gr = M - 1;
            const unsigned short* gp = Xb + gr * K + k0 + gsrc * 8;
            __builtin_amdgcn_global_load_lds((gv_t*)gp, (lv_t*)(xs + chunk * 512 + ln * 8), 16, 0, 0);
        }
        // stage Wt tile (rows = output cols)
#pragma unroll
        for (int i = 0; i < 4; ++i) {
            const int chunk = wv * 4 + i;
            const int row = chunk * 8 + (ln >> 3);
            const int gsrc = (ln & 7) ^ (row & 7);
            const unsigned short* gp = Wt + (size_t)(col0 + row) * K + k0 + gsrc * 8;
            __builtin_amdgcn_global_load_lds((gv_t*)gp, (lv_t*)(wsx + chunk * 512 + ln * 8), 16, 0, 0);
        }
        __syncthreads();

#pragma unroll
        for (int kk = 0; kk < 2; ++kk) {
            bf16x8 a[4], b[4];
            const int g = kk * 4 + (ln >> 4);
#pragma unroll
            for (int m = 0; m < 4; ++m) {
                const int row = wr2 * 64 + m * 16 + (ln & 15);
                const int s = g ^ (row & 7);
                a[m] = *(const bf16x8*)&xs[row * 64 + s * 8];
            }
#pragma unroll
            for (int n = 0; n < 4; ++n) {
                const int row = wc2 * 64 + n * 16 + (ln & 15);
                const int s = g ^ (row & 7);
                b[n] = *(const bf16x8*)&wsx[row * 64 + s * 8];
            }
#pragma unroll
            for (int m = 0; m < 4; ++m)
#pragma unroll
                for (int n = 0; n < 4; ++n)
                    acc[m][n] = __builtin_amdgcn_mfma_f32_16x16x32_bf16(a[m], b[n], acc[m][n], 0, 0, 0);
        }
        __syncthreads();
    }

    // epilogue: C/D map col=lane&15, row=4*(lane>>4)+q
    float bj[4];
#pragma unroll
    for (int n = 0; n < 4; ++n)
        bj[n] = BIAS ? bias[col0 + wc2 * 64 + n * 16 + (ln & 15)] : 0.f;

#pragma unroll
    for (int m = 0; m < 4; ++m) {
        const long rbase = row0 + wr2 * 64 + m * 16 + 4 * (ln >> 4);
#pragma unroll
        for (int n = 0; n < 4; ++n) {
            const int col = col0 + wc2 * 64 + n * 16 + (ln & 15);
#pragma unroll
            for (int q = 0; q < 4; ++q) {
                const long r = rbase + q;
                if (r >= M) continue;
                Yb[r * HID + col] = f2b(acc[m][n][q] + bj[n]);
            }
        }
    }

    if (DOTS) {
        float alv[4], arv[4];
#pragma unroll
        for (int n = 0; n < 4; ++n) {
            const int col = col0 + wc2 * 64 + n * 16 + (ln & 15);
            alv[n] = al[col];
            arv[n] = ar[col];
        }
#pragma unroll
        for (int m = 0; m < 4; ++m) {
#pragma unroll
            for (int q = 0; q < 4; ++q) {
                float pl = 0.f, pr = 0.f;
#pragma unroll
                for (int n = 0; n < 4; ++n) {
                    pl = fmaf(acc[m][n][q], alv[n], pl);
                    pr = fmaf(acc[m][n][q], arv[n], pr);
                }
#pragma unroll
                for (int o = 1; o < 16; o <<= 1) {
                    pl += __shfl_xor(pl, o);
                    pr += __shfl_xor(pr, o);
                }
                if ((ln & 15) == 0) {
                    const long r = row0 + wr2 * 64 + m * 16 + 4 * (ln >> 4) + q;
                    if (r < M) {
                        atomicAdd(&el[r], pl);
                        atomicAdd(&er[r], pr);
                    }
                }
            }
        }
    }
}

// ======================= CSR build (per launch) =======================
__global__ void hist_dst(const int* __restrict__ dst, int* __restrict__ deg) {
    int i = blockIdx.x * 256 + threadIdx.x;
    if (i < N_EDGES) atomicAdd(&deg[dst[i]], 1);
}

__global__ __launch_bounds__(1024) void scan_block(const int* __restrict__ deg,
                                                   int* __restrict__ sexc,
                                                   int* __restrict__ bsum) {
    int t = threadIdx.x, gid = blockIdx.x * 1024 + t;
    int v = (gid < N_NODES) ? deg[gid] : 0;
    int lane = t & 63, wv = t >> 6;
    int x = v;
#pragma unroll
    for (int o = 1; o < 64; o <<= 1) {
        int y = __shfl_up(x, o);
        if (lane >= o) x += y;
    }
    __shared__ int wsum[16];
    if (lane == 63) wsum[wv] = x;
    __syncthreads();
    if (t == 0) {
        int a = 0;
#pragma unroll
        for (int i = 0; i < 16; ++i) { int tt = wsum[i]; wsum[i] = a; a += tt; }
        bsum[blockIdx.x] = a;
    }
    __syncthreads();
    sexc[gid] = (x - v) + wsum[wv];
}

__global__ __launch_bounds__(128) void scan_partials(int* __restrict__ bsum,
                                                     int* __restrict__ offsets) {
    __shared__ int s[128];
    int t = threadIdx.x;
    int v = (t < NB) ? bsum[t] : 0;
    s[t] = v;
    __syncthreads();
    for (int o = 1; o < 128; o <<= 1) {
        int y = (t >= o) ? s[t - o] : 0;
        __syncthreads();
        s[t] += y;
        __syncthreads();
    }
    if (t < NB) bsum[t] = s[t] - v;
    if (t == 127) offsets[N_NODES] = s[127];
}

__global__ __launch_bounds__(1024) void scan_add(const int* __restrict__ sexc,
                                                 const int* __restrict__ bsum,
                                                 int* __restrict__ offsets) {
    int gid = blockIdx.x * 1024 + threadIdx.x;
    if (gid < N_NODES) offsets[gid] = sexc[gid] + bsum[blockIdx.x];
}

__global__ void csr_fill(const int* __restrict__ src, const int* __restrict__ dst,
                         const int* __restrict__ offsets, int* __restrict__ cnt,
                         int* __restrict__ csrc) {
    int i = blockIdx.x * 256 + threadIdx.x;
    if (i < N_EDGES) {
        int d = dst[i];
        int slot = offsets[d] + atomicAdd(&cnt[d], 1);
        csrc[slot] = src[i];
    }
}

// goff[g] = lower_bound(graph_ids, g); graph_ids is sorted.
__global__ void graph_offsets(const int* __restrict__ gid, int* __restrict__ goff) {
    int g = blockIdx.x * 256 + threadIdx.x;
    if (g > N_GRAPHS) return;
    int lo = 0, hi = N_NODES;
    while (lo < hi) {
        int mid = (lo + hi) >> 1;
        if (gid[mid] < g) lo = mid + 1; else hi = mid;
    }
    goff[g] = lo;
}

// ===================== per-layer small kernels =====================
// One THREAD per node: segment softmax over its CSR edges -> alpha[c].
__global__ __launch_bounds__(256) void alpha_kernel(const int* __restrict__ offs,
                                                    const int* __restrict__ csrc,
                                                    const float* __restrict__ el,
                                                    const float* __restrict__ er,
                                                    float* __restrict__ alpha) {
    int n = blockIdx.x * 256 + threadIdx.x;
    if (n >= N_NODES) return;
    const int beg = offs[n], end = offs[n + 1];
    if (beg == end) return;
    const float ern = er[n];
    float m = -3.4e38f;
    for (int c = beg; c < end; ++c) {
        float v = el[csrc[c]] + ern;
        v = (v >= 0.f) ? v : NEG_SLOPE * v;
        alpha[c] = v;                      // stash e
        m = fmaxf(m, v);
    }
    float s = 0.f;
    for (int c = beg; c < end; ++c) {
        float a = __expf(alpha[c] - m);
        alpha[c] = a;
        s += a;
    }
    const float inv = 1.f / (s + EPS);
    for (int c = beg; c < end; ++c) alpha[c] *= inv;
}

// One wave per dst node: single-pass weighted gather + residual + ReLU.
__global__ __launch_bounds__(256) void gather_attn(const int* __restrict__ offs,
                                                   const int* __restrict__ csrc,
                                                   const float* __restrict__ alpha,
                                                   const unsigned short* __restrict__ z,
                                                   unsigned short* __restrict__ Ab) {
    const int n = blockIdx.x * 4 + (threadIdx.x >> 6);
    const int lane = threadIdx.x & 63;
    const int beg = offs[n], end = offs[n + 1];

    float4 acc = make_float4(0.f, 0.f, 0.f, 0.f);
    for (int c = beg; c < end; ++c) {
        float a = alpha[c];                       // wave-uniform
        int sc = csrc[c];
        ushort4 zz = ((const ushort4*)(z + (size_t)sc * HID))[lane];
        acc.x = fmaf(a, b2f(zz.x), acc.x);
        acc.y = fmaf(a, b2f(zz.y), acc.y);
        acc.z = fmaf(a, b2f(zz.z), acc.z);
        acc.w = fmaf(a, b2f(zz.w), acc.w);
    }

    ushort4* Ap = (ushort4*)(Ab + (size_t)n * HID);
    ushort4 hh = Ap[lane];
    ushort4 ob;
    ob.x = f2b(fmaxf(b2f(hh.x) + acc.x, 0.f));
    ob.y = f2b(fmaxf(b2f(hh.y) + acc.y, 0.f));
    ob.z = f2b(fmaxf(b2f(hh.z) + acc.z, 0.f));
    ob.w = f2b(fmaxf(b2f(hh.w) + acc.w, 0.f));
    Ap[lane] = ob;
}

// g[gi,:] = sum of bf16 h rows in [goff[gi], goff[gi+1]) — sorted, no atomics
__global__ __launch_bounds__(256) void pool_seg(const unsigned short* __restrict__ h,
                                                const int* __restrict__ goff,
                                                float* __restrict__ g) {
    const int gi = blockIdx.x, t = threadIdx.x;
    const int beg = goff[gi], end = goff[gi + 1];
    float acc = 0.f;
    for (int n = beg; n < end; ++n) acc += b2f(h[(size_t)n * HID + t]);
    g[(size_t)gi * HID + t] = acc;
}

// fused MLP: relu(g@w1+b1) -> relu(@w2+b2) -> @w3+b3
__global__ void mlp_kernel(const float* __restrict__ g,
                           const float* __restrict__ w1, const float* __restrict__ b1,
                           const float* __restrict__ w2, const float* __restrict__ b2,
                           const float* __restrict__ w3, const float* __restrict__ b3,
                           float* __restrict__ out) {
    int gi = blockIdx.x, t = threadIdx.x;
    __shared__ float x[HID];
    __shared__ float y1[HID / 2];
    __shared__ float y2[HID / 4];
    x[t] = g[gi * HID + t];
    __syncthreads();
    if (t < HID / 2) {
        float a = b1[t];
#pragma unroll 8
        for (int k = 0; k < HID; ++k) a += x[k] * w1[k * (HID / 2) + t];
        y1[t] = fmaxf(a, 0.f);
    }
    __syncthreads();
    if (t < HID / 4) {
        float a = b2[t];
#pragma unroll 8
        for (int k = 0; k < HID / 2; ++k) a += y1[k] * w2[k * (HID / 4) + t];
        y2[t] = fmaxf(a, 0.f);
    }
    __syncthreads();
    if (t < 64) {
        float p = y2[t] * w3[t];
#pragma unroll
        for (int off = 32; off > 0; off >>= 1) p += __shfl_down(p, off);
        if (t == 0) out[gi] = p + b3[0];
    }
}

extern "C" void kernel_launch(void* const* d_in, const int* in_sizes, int n_in,
                              void* d_out, int out_size, void* d_ws, size_t ws_size,
                              hipStream_t stream) {
    const float* node_feats = (const float*)d_in[0];
    const int*   src        = (const int*)d_in[1];
    const int*   dst        = (const int*)d_in[2];
    const int*   graph_ids  = (const int*)d_in[3];
    const float* w_embed    = (const float*)d_in[4];
    const float* b_embed    = (const float*)d_in[5];
    const float* gat_W      = (const float*)d_in[6];
    const float* gat_al     = (const float*)d_in[7];
    const float* gat_ar     = (const float*)d_in[8];
    const float* w1         = (const float*)d_in[9];
    const float* b1         = (const float*)d_in[10];
    const float* w2         = (const float*)d_in[11];
    const float* b2         = (const float*)d_in[12];
    const float* w3         = (const float*)d_in[13];
    const float* b3         = (const float*)d_in[14];
    float* out = (float*)d_out;

    char* ws = (char*)d_ws;
    size_t off = 0;
    auto alloc = [&](size_t bytes) { char* p = ws + off; off += (bytes + 255) & ~size_t(255); return p; };
    unsigned short* Ab      = (unsigned short*)alloc((size_t)N_NODES * HID * 2); // h (bf16)
    unsigned short* Zb      = (unsigned short*)alloc((size_t)N_NODES * HID * 2); // z (bf16); aliases nfb
    unsigned short* Wt      = (unsigned short*)alloc((size_t)HID * HID * 2);     // W^T bf16
    float*          eler    = (float*)alloc((size_t)2 * N_NODES * 4);            // el | er
    float*          alpha   = (float*)alloc((size_t)N_EDGES * 4);
    int*            deg     = (int*)alloc((size_t)N_NODES * 4);
    int*            cnt     = (int*)alloc((size_t)N_NODES * 4);
    int*            sexc    = (int*)alloc((size_t)NB * 1024 * 4);
    int*            bsum    = (int*)alloc(128 * 4);
    int*            offsets = (int*)alloc((size_t)(N_NODES + 1) * 4);
    int*            csrc    = (int*)alloc((size_t)N_EDGES * 4);
    int*            goff    = (int*)alloc((size_t)(N_GRAPHS + 1) * 4);
    float*          g       = (float*)alloc((size_t)N_GRAPHS * HID * 4);
    float*          el      = eler;
    float*          er      = eler + N_NODES;
    unsigned short* nfb     = Zb;  // node_feats bf16, dead before Zb first written

    // ---- CSR build (graph static across layers) + graph offsets ----
    hipMemsetAsync(deg, 0, (size_t)N_NODES * 4, stream);
    hipMemsetAsync(cnt, 0, (size_t)N_NODES * 4, stream);
    hist_dst<<<(N_EDGES + 255) / 256, 256, 0, stream>>>(dst, deg);
    scan_block<<<NB, 1024, 0, stream>>>(deg, sexc, bsum);
    scan_partials<<<1, 128, 0, stream>>>(bsum, offsets);
    scan_add<<<NB, 1024, 0, stream>>>(sexc, bsum, offsets);
    csr_fill<<<(N_EDGES + 255) / 256, 256, 0, stream>>>(src, dst, offsets, cnt, csrc);
    graph_offsets<<<(N_GRAPHS + 256) / 256, 256, 0, stream>>>(graph_ids, goff);

    dim3 ggrid((N_NODES + 127) / 128, HID / 128);

    // ---- embed: h = nf @ w_embed + b (MFMA, bf16 in/out) ----
    convert_f32_bf16<<<(N_NODES * NODE_DIM / 4 + 255) / 256, 256, 0, stream>>>(node_feats, nfb, N_NODES * NODE_DIM / 4);
    transpose_bf16<<<dim3(NODE_DIM / 32, HID / 32), 256, 0, stream>>>(w_embed, Wt, NODE_DIM);
    gemm_mfma<NODE_DIM, true, false><<<ggrid, 256, 0, stream>>>(
        nfb, Wt, b_embed, Ab, nullptr, nullptr, nullptr, nullptr, N_NODES);

    for (int l = 0; l < N_GAT; ++l) {
        const float* W  = gat_W  + (size_t)l * HID * HID;
        const float* al = gat_al + (size_t)l * HID;
        const float* ar = gat_ar + (size_t)l * HID;

        transpose_bf16<<<dim3(HID / 32, HID / 32), 256, 0, stream>>>(W, Wt, HID);
        hipMemsetAsync(eler, 0, (size_t)2 * N_NODES * 4, stream);
        gemm_mfma<HID, false, true><<<ggrid, 256, 0, stream>>>(
            Ab, Wt, nullptr, Zb, al, ar, el, er, N_NODES);
        alpha_kernel<<<(N_NODES + 255) / 256, 256, 0, stream>>>(offsets, csrc, el, er, alpha);
        gather_attn<<<N_NODES / 4, 256, 0, stream>>>(offsets, csrc, alpha, Zb, Ab);
    }

    pool_seg<<<N_GRAPHS, 256, 0, stream>>>(Ab, goff, g);
    mlp_kernel<<<N_GRAPHS, HID, 0, stream>>>(g, w1, b1, w2, b2, w3, b3, out);
}

// Round 9
// 510.668 us; speedup vs baseline: 8.5368x; 1.0236x over previous
//
#include <hip/hip_runtime.h>
#include <hip/hip_bf16.h>

#define N_NODES 100000
#define N_EDGES 200000
#define N_GRAPHS 4096
#define NODE_DIM 64
#define HID 256
#define N_GAT 4
#define NEG_SLOPE 0.2f
#define EPS 1e-9f
#define NB 98  // ceil(N_NODES/1024)

typedef const __attribute__((address_space(1))) void gv_t;
typedef __attribute__((address_space(3))) void lv_t;
typedef __attribute__((ext_vector_type(8))) short bf16x8;
typedef __attribute__((ext_vector_type(4))) float f32x4;

__device__ __forceinline__ float b2f(unsigned short u) {
    return __uint_as_float(((unsigned)u) << 16);
}
__device__ __forceinline__ unsigned short f2b(float f) {   // RNE
    unsigned u = __float_as_uint(f);
    return (unsigned short)((u + 0x7fffu + ((u >> 16) & 1u)) >> 16);
}

// ==================== converters ====================
__global__ void convert_f32_bf16(const float* __restrict__ src,
                                 unsigned short* __restrict__ dst, int n4) {
    int i = blockIdx.x * 256 + threadIdx.x;
    if (i >= n4) return;
    float4 v = ((const float4*)src)[i];
    ushort4 o;
    o.x = f2b(v.x); o.y = f2b(v.y); o.z = f2b(v.z); o.w = f2b(v.w);
    ((ushort4*)dst)[i] = o;
}

// Wt[c][k] = bf16(W[k][c]);  W is [K][256], Wt is [256][K]
__global__ __launch_bounds__(256) void transpose_bf16(const float* __restrict__ W,
                                                      unsigned short* __restrict__ Wt,
                                                      int K) {
    __shared__ float tile[32][33];
    const int kb = blockIdx.x * 32, cb = blockIdx.y * 32;
    const int tr = threadIdx.x >> 5, tc = threadIdx.x & 31;
#pragma unroll
    for (int i = 0; i < 4; ++i)
        tile[tr + i * 8][tc] = W[(size_t)(kb + tr + i * 8) * HID + cb + tc];
    __syncthreads();
#pragma unroll
    for (int i = 0; i < 4; ++i)
        Wt[(size_t)(cb + tr + i * 8) * K + kb + tc] = f2b(tile[tc][tr + i * 8]);
}

// ==================== MFMA GEMM, 2-phase pipelined ====================
// Y[M,256] = X[M,K](bf16) @ Wt[256,K](bf16, pre-transposed) (+bias).
// 128x128 block tile, 4 waves (64x64 each), 4x4 frags of 16x16x32 bf16 MFMA.
// DOUBLE-BUFFERED LDS: STAGE(t+1) issued before COMPUTE(t); the iteration-end
// __syncthreads() (vmcnt(0)+barrier) drains loads that overlapped compute.
// NT is compile-time; full unroll makes buffer indices static (AA-provable
// disjoint -> no spurious vmcnt waits before ds_read).
// Both LDS tiles [row][KC] with 16B-granule XOR swizzle (g ^= row&7), applied
// on the GLOBAL source address (global_load_lds dest stays linear).
// If DOTS: el[r] += z[r]·al, er[r] += z[r]·ar from f32 acc (el/er pre-zeroed).
template <int K, bool BIAS, bool DOTS>
__global__ __launch_bounds__(256) void gemm_mfma(const unsigned short* __restrict__ Xb,
                                                 const unsigned short* __restrict__ Wt,
                                                 const float* __restrict__ bias,
                                                 unsigned short* __restrict__ Yb,
                                                 const float* __restrict__ al,
                                                 const float* __restrict__ ar,
                                                 float* __restrict__ el,
                                                 float* __restrict__ er,
                                                 int M) {
    constexpr int KC = 64;
    constexpr int NT = K / KC;
    __shared__ unsigned short xs[2][128 * KC];   // [buf][row*64+..] bf16, swizzled
    __shared__ unsigned short wsx[2][128 * KC];
    const int t = threadIdx.x, wv = t >> 6, ln = t & 63;
    const int wr2 = wv >> 1, wc2 = wv & 1;       // wave quadrant (2x2)
    const long row0 = (long)blockIdx.x * 128;
    const int  col0 = blockIdx.y * 128;

    auto stage = [&](int buf, int k0) {
#pragma unroll
        for (int i = 0; i < 4; ++i) {
            const int chunk = wv * 4 + i;
            const int row = chunk * 8 + (ln >> 3);
            const int gsrc = (ln & 7) ^ (row & 7);
            long gr = row0 + row; if (gr >= M) gr = M - 1;
            const unsigned short* gp = Xb + gr * K + k0 + gsrc * 8;
            __builtin_amdgcn_global_load_lds((gv_t*)gp, (lv_t*)(&xs[buf][chunk * 512 + ln * 8]), 16, 0, 0);
        }
#pragma unroll
        for (int i = 0; i < 4; ++i) {
            const int chunk = wv * 4 + i;
            const int row = chunk * 8 + (ln >> 3);
            const int gsrc = (ln & 7) ^ (row & 7);
            const unsigned short* gp = Wt + (size_t)(col0 + row) * K + k0 + gsrc * 8;
            __builtin_amdgcn_global_load_lds((gv_t*)gp, (lv_t*)(&wsx[buf][chunk * 512 + ln * 8]), 16, 0, 0);
        }
    };

    f32x4 acc[4][4];
#pragma unroll
    for (int m = 0; m < 4; ++m)
#pragma unroll
        for (int n = 0; n < 4; ++n) acc[m][n] = (f32x4){0.f, 0.f, 0.f, 0.f};

    stage(0, 0);
    __syncthreads();

#pragma unroll
    for (int tt = 0; tt < NT; ++tt) {
        const int cur = tt & 1;
        if (tt + 1 < NT) stage(cur ^ 1, (tt + 1) * KC);   // prefetch overlaps compute

#pragma unroll
        for (int kk = 0; kk < 2; ++kk) {
            bf16x8 a[4], b[4];
            const int g = kk * 4 + (ln >> 4);
#pragma unroll
            for (int m = 0; m < 4; ++m) {
                const int row = wr2 * 64 + m * 16 + (ln & 15);
                const int s = g ^ (row & 7);
                a[m] = *(const bf16x8*)&xs[cur][row * 64 + s * 8];
            }
#pragma unroll
            for (int n = 0; n < 4; ++n) {
                const int row = wc2 * 64 + n * 16 + (ln & 15);
                const int s = g ^ (row & 7);
                b[n] = *(const bf16x8*)&wsx[cur][row * 64 + s * 8];
            }
#pragma unroll
            for (int m = 0; m < 4; ++m)
#pragma unroll
                for (int n = 0; n < 4; ++n)
                    acc[m][n] = __builtin_amdgcn_mfma_f32_16x16x32_bf16(a[m], b[n], acc[m][n], 0, 0, 0);
        }
        __syncthreads();   // drains the prefetch (vmcnt 0) + protects buf reuse
    }

    // epilogue: C/D map col=lane&15, row=4*(lane>>4)+q
    float bj[4];
#pragma unroll
    for (int n = 0; n < 4; ++n)
        bj[n] = BIAS ? bias[col0 + wc2 * 64 + n * 16 + (ln & 15)] : 0.f;

#pragma unroll
    for (int m = 0; m < 4; ++m) {
        const long rbase = row0 + wr2 * 64 + m * 16 + 4 * (ln >> 4);
#pragma unroll
        for (int n = 0; n < 4; ++n) {
            const int col = col0 + wc2 * 64 + n * 16 + (ln & 15);
#pragma unroll
            for (int q = 0; q < 4; ++q) {
                const long r = rbase + q;
                if (r >= M) continue;
                Yb[r * HID + col] = f2b(acc[m][n][q] + bj[n]);
            }
        }
    }

    if (DOTS) {
        float alv[4], arv[4];
#pragma unroll
        for (int n = 0; n < 4; ++n) {
            const int col = col0 + wc2 * 64 + n * 16 + (ln & 15);
            alv[n] = al[col];
            arv[n] = ar[col];
        }
#pragma unroll
        for (int m = 0; m < 4; ++m) {
#pragma unroll
            for (int q = 0; q < 4; ++q) {
                float pl = 0.f, pr = 0.f;
#pragma unroll
                for (int n = 0; n < 4; ++n) {
                    pl = fmaf(acc[m][n][q], alv[n], pl);
                    pr = fmaf(acc[m][n][q], arv[n], pr);
                }
#pragma unroll
                for (int o = 1; o < 16; o <<= 1) {
                    pl += __shfl_xor(pl, o);
                    pr += __shfl_xor(pr, o);
                }
                if ((ln & 15) == 0) {
                    const long r = row0 + wr2 * 64 + m * 16 + 4 * (ln >> 4) + q;
                    if (r < M) {
                        atomicAdd(&el[r], pl);
                        atomicAdd(&er[r], pr);
                    }
                }
            }
        }
    }
}

// ======================= CSR build (per launch) =======================
__global__ void hist_dst(const int* __restrict__ dst, int* __restrict__ deg) {
    int i = blockIdx.x * 256 + threadIdx.x;
    if (i < N_EDGES) atomicAdd(&deg[dst[i]], 1);
}

__global__ __launch_bounds__(1024) void scan_block(const int* __restrict__ deg,
                                                   int* __restrict__ sexc,
                                                   int* __restrict__ bsum) {
    int t = threadIdx.x, gid = blockIdx.x * 1024 + t;
    int v = (gid < N_NODES) ? deg[gid] : 0;
    int lane = t & 63, wv = t >> 6;
    int x = v;
#pragma unroll
    for (int o = 1; o < 64; o <<= 1) {
        int y = __shfl_up(x, o);
        if (lane >= o) x += y;
    }
    __shared__ int wsum[16];
    if (lane == 63) wsum[wv] = x;
    __syncthreads();
    if (t == 0) {
        int a = 0;
#pragma unroll
        for (int i = 0; i < 16; ++i) { int tt = wsum[i]; wsum[i] = a; a += tt; }
        bsum[blockIdx.x] = a;
    }
    __syncthreads();
    sexc[gid] = (x - v) + wsum[wv];
}

__global__ __launch_bounds__(128) void scan_partials(int* __restrict__ bsum,
                                                     int* __restrict__ offsets) {
    __shared__ int s[128];
    int t = threadIdx.x;
    int v = (t < NB) ? bsum[t] : 0;
    s[t] = v;
    __syncthreads();
    for (int o = 1; o < 128; o <<= 1) {
        int y = (t >= o) ? s[t - o] : 0;
        __syncthreads();
        s[t] += y;
        __syncthreads();
    }
    if (t < NB) bsum[t] = s[t] - v;
    if (t == 127) offsets[N_NODES] = s[127];
}

// writes offsets AND initializes cnt (= next free slot) in one pass
__global__ __launch_bounds__(1024) void scan_add(const int* __restrict__ sexc,
                                                 const int* __restrict__ bsum,
                                                 int* __restrict__ offsets,
                                                 int* __restrict__ cnt) {
    int gid = blockIdx.x * 1024 + threadIdx.x;
    if (gid < N_NODES) {
        int v = sexc[gid] + bsum[blockIdx.x];
        offsets[gid] = v;
        cnt[gid] = v;
    }
}

__global__ void csr_fill(const int* __restrict__ src, const int* __restrict__ dst,
                         int* __restrict__ cnt, int* __restrict__ csrc) {
    int i = blockIdx.x * 256 + threadIdx.x;
    if (i < N_EDGES) {
        int slot = atomicAdd(&cnt[dst[i]], 1);
        csrc[slot] = src[i];
    }
}

// goff[g] = lower_bound(graph_ids, g); graph_ids is sorted.
__global__ void graph_offsets(const int* __restrict__ gid, int* __restrict__ goff) {
    int g = blockIdx.x * 256 + threadIdx.x;
    if (g > N_GRAPHS) return;
    int lo = 0, hi = N_NODES;
    while (lo < hi) {
        int mid = (lo + hi) >> 1;
        if (gid[mid] < g) lo = mid + 1; else hi = mid;
    }
    goff[g] = lo;
}

// ===================== per-layer small kernels =====================
// One THREAD per node: segment softmax over its CSR edges -> alpha[c].
__global__ __launch_bounds__(256) void alpha_kernel(const int* __restrict__ offs,
                                                    const int* __restrict__ csrc,
                                                    const float* __restrict__ el,
                                                    const float* __restrict__ er,
                                                    float* __restrict__ alpha) {
    int n = blockIdx.x * 256 + threadIdx.x;
    if (n >= N_NODES) return;
    const int beg = offs[n], end = offs[n + 1];
    if (beg == end) return;
    const float ern = er[n];
    float m = -3.4e38f;
    for (int c = beg; c < end; ++c) {
        float v = el[csrc[c]] + ern;
        v = (v >= 0.f) ? v : NEG_SLOPE * v;
        alpha[c] = v;                      // stash e
        m = fmaxf(m, v);
    }
    float s = 0.f;
    for (int c = beg; c < end; ++c) {
        float a = __expf(alpha[c] - m);
        alpha[c] = a;
        s += a;
    }
    const float inv = 1.f / (s + EPS);
    for (int c = beg; c < end; ++c) alpha[c] *= inv;
}

// One wave per dst node: single-pass weighted gather + residual + ReLU.
// Edge loop unrolled x2 so both neighbor rows are in flight together.
__global__ __launch_bounds__(256) void gather_attn(const int* __restrict__ offs,
                                                   const int* __restrict__ csrc,
                                                   const float* __restrict__ alpha,
                                                   const unsigned short* __restrict__ z,
                                                   unsigned short* __restrict__ Ab) {
    const int n = blockIdx.x * 4 + (threadIdx.x >> 6);
    const int lane = threadIdx.x & 63;
    const int beg = offs[n], end = offs[n + 1];

    float4 acc = make_float4(0.f, 0.f, 0.f, 0.f);
    int c = beg;
    for (; c + 1 < end; c += 2) {
        float a0 = alpha[c], a1 = alpha[c + 1];
        int s0 = csrc[c], s1 = csrc[c + 1];
        ushort4 z0 = ((const ushort4*)(z + (size_t)s0 * HID))[lane];
        ushort4 z1 = ((const ushort4*)(z + (size_t)s1 * HID))[lane];
        acc.x = fmaf(a0, b2f(z0.x), acc.x); acc.x = fmaf(a1, b2f(z1.x), acc.x);
        acc.y = fmaf(a0, b2f(z0.y), acc.y); acc.y = fmaf(a1, b2f(z1.y), acc.y);
        acc.z = fmaf(a0, b2f(z0.z), acc.z); acc.z = fmaf(a1, b2f(z1.z), acc.z);
        acc.w = fmaf(a0, b2f(z0.w), acc.w); acc.w = fmaf(a1, b2f(z1.w), acc.w);
    }
    if (c < end) {
        float a = alpha[c];
        int sc = csrc[c];
        ushort4 zz = ((const ushort4*)(z + (size_t)sc * HID))[lane];
        acc.x = fmaf(a, b2f(zz.x), acc.x);
        acc.y = fmaf(a, b2f(zz.y), acc.y);
        acc.z = fmaf(a, b2f(zz.z), acc.z);
        acc.w = fmaf(a, b2f(zz.w), acc.w);
    }

    ushort4* Ap = (ushort4*)(Ab + (size_t)n * HID);
    ushort4 hh = Ap[lane];
    ushort4 ob;
    ob.x = f2b(fmaxf(b2f(hh.x) + acc.x, 0.f));
    ob.y = f2b(fmaxf(b2f(hh.y) + acc.y, 0.f));
    ob.z = f2b(fmaxf(b2f(hh.z) + acc.z, 0.f));
    ob.w = f2b(fmaxf(b2f(hh.w) + acc.w, 0.f));
    Ap[lane] = ob;
}

// g[gi,:] = sum of bf16 h rows in [goff[gi], goff[gi+1]) — sorted, no atomics
__global__ __launch_bounds__(256) void pool_seg(const unsigned short* __restrict__ h,
                                                const int* __restrict__ goff,
                                                float* __restrict__ g) {
    const int gi = blockIdx.x, t = threadIdx.x;
    const int beg = goff[gi], end = goff[gi + 1];
    float acc = 0.f;
    for (int n = beg; n < end; ++n) acc += b2f(h[(size_t)n * HID + t]);
    g[(size_t)gi * HID + t] = acc;
}

// fused MLP: relu(g@w1+b1) -> relu(@w2+b2) -> @w3+b3
__global__ void mlp_kernel(const float* __restrict__ g,
                           const float* __restrict__ w1, const float* __restrict__ b1,
                           const float* __restrict__ w2, const float* __restrict__ b2,
                           const float* __restrict__ w3, const float* __restrict__ b3,
                           float* __restrict__ out) {
    int gi = blockIdx.x, t = threadIdx.x;
    __shared__ float x[HID];
    __shared__ float y1[HID / 2];
    __shared__ float y2[HID / 4];
    x[t] = g[gi * HID + t];
    __syncthreads();
    if (t < HID / 2) {
        float a = b1[t];
#pragma unroll 8
        for (int k = 0; k < HID; ++k) a += x[k] * w1[k * (HID / 2) + t];
        y1[t] = fmaxf(a, 0.f);
    }
    __syncthreads();
    if (t < HID / 4) {
        float a = b2[t];
#pragma unroll 8
        for (int k = 0; k < HID / 2; ++k) a += y1[k] * w2[k * (HID / 4) + t];
        y2[t] = fmaxf(a, 0.f);
    }
    __syncthreads();
    if (t < 64) {
        float p = y2[t] * w3[t];
#pragma unroll
        for (int off = 32; off > 0; off >>= 1) p += __shfl_down(p, off);
        if (t == 0) out[gi] = p + b3[0];
    }
}

extern "C" void kernel_launch(void* const* d_in, const int* in_sizes, int n_in,
                              void* d_out, int out_size, void* d_ws, size_t ws_size,
                              hipStream_t stream) {
    const float* node_feats = (const float*)d_in[0];
    const int*   src        = (const int*)d_in[1];
    const int*   dst        = (const int*)d_in[2];
    const int*   graph_ids  = (const int*)d_in[3];
    const float* w_embed    = (const float*)d_in[4];
    const float* b_embed    = (const float*)d_in[5];
    const float* gat_W      = (const float*)d_in[6];
    const float* gat_al     = (const float*)d_in[7];
    const float* gat_ar     = (const float*)d_in[8];
    const float* w1         = (const float*)d_in[9];
    const float* b1         = (const float*)d_in[10];
    const float* w2         = (const float*)d_in[11];
    const float* b2         = (const float*)d_in[12];
    const float* w3         = (const float*)d_in[13];
    const float* b3         = (const float*)d_in[14];
    float* out = (float*)d_out;

    char* ws = (char*)d_ws;
    size_t off = 0;
    auto alloc = [&](size_t bytes) { char* p = ws + off; off += (bytes + 255) & ~size_t(255); return p; };
    unsigned short* Ab      = (unsigned short*)alloc((size_t)N_NODES * HID * 2); // h (bf16)
    unsigned short* Zb      = (unsigned short*)alloc((size_t)N_NODES * HID * 2); // z (bf16); aliases nfb
    unsigned short* Wt      = (unsigned short*)alloc((size_t)HID * HID * 2);     // W^T bf16
    float*          eler    = (float*)alloc((size_t)2 * N_NODES * 4);            // el | er
    float*          alpha   = (float*)alloc((size_t)N_EDGES * 4);
    int*            deg     = (int*)alloc((size_t)N_NODES * 4);
    int*            cnt     = (int*)alloc((size_t)N_NODES * 4);
    int*            sexc    = (int*)alloc((size_t)NB * 1024 * 4);
    int*            bsum    = (int*)alloc(128 * 4);
    int*            offsets = (int*)alloc((size_t)(N_NODES + 1) * 4);
    int*            csrc    = (int*)alloc((size_t)N_EDGES * 4);
    int*            goff    = (int*)alloc((size_t)(N_GRAPHS + 1) * 4);
    float*          g       = (float*)alloc((size_t)N_GRAPHS * HID * 4);
    float*          el      = eler;
    float*          er      = eler + N_NODES;
    unsigned short* nfb     = Zb;  // node_feats bf16, dead before Zb first written

    // ---- CSR build (graph static across layers) + graph offsets ----
    hipMemsetAsync(deg, 0, (size_t)N_NODES * 4, stream);
    hist_dst<<<(N_EDGES + 255) / 256, 256, 0, stream>>>(dst, deg);
    scan_block<<<NB, 1024, 0, stream>>>(deg, sexc, bsum);
    scan_partials<<<1, 128, 0, stream>>>(bsum, offsets);
    scan_add<<<NB, 1024, 0, stream>>>(sexc, bsum, offsets, cnt);
    csr_fill<<<(N_EDGES + 255) / 256, 256, 0, stream>>>(src, dst, cnt, csrc);
    graph_offsets<<<(N_GRAPHS + 256) / 256, 256, 0, stream>>>(graph_ids, goff);

    dim3 ggrid((N_NODES + 127) / 128, HID / 128);

    // ---- embed: h = nf @ w_embed + b (MFMA, bf16 in/out) ----
    convert_f32_bf16<<<(N_NODES * NODE_DIM / 4 + 255) / 256, 256, 0, stream>>>(node_feats, nfb, N_NODES * NODE_DIM / 4);
    transpose_bf16<<<dim3(NODE_DIM / 32, HID / 32), 256, 0, stream>>>(w_embed, Wt, NODE_DIM);
    gemm_mfma<NODE_DIM, true, false><<<ggrid, 256, 0, stream>>>(
        nfb, Wt, b_embed, Ab, nullptr, nullptr, nullptr, nullptr, N_NODES);

    for (int l = 0; l < N_GAT; ++l) {
        const float* W  = gat_W  + (size_t)l * HID * HID;
        const float* al = gat_al + (size_t)l * HID;
        const float* ar = gat_ar + (size_t)l * HID;

        transpose_bf16<<<dim3(HID / 32, HID / 32), 256, 0, stream>>>(W, Wt, HID);
        hipMemsetAsync(eler, 0, (size_t)2 * N_NODES * 4, stream);
        gemm_mfma<HID, false, true><<<ggrid, 256, 0, stream>>>(
            Ab, Wt, nullptr, Zb, al, ar, el, er, N_NODES);
        alpha_kernel<<<(N_NODES + 255) / 256, 256, 0, stream>>>(offsets, csrc, el, er, alpha);
        gather_attn<<<N_NODES / 4, 256, 0, stream>>>(offsets, csrc, alpha, Zb, Ab);
    }

    pool_seg<<<N_GRAPHS, 256, 0, stream>>>(Ab, goff, g);
    mlp_kernel<<<N_GRAPHS, HID, 0, stream>>>(g, w1, b1, w2, b2, w3, b3, out);
}

// Round 10
// 509.145 us; speedup vs baseline: 8.5623x; 1.0030x over previous
//
#include <hip/hip_runtime.h>
#include <hip/hip_bf16.h>

#define N_NODES 100000
#define N_EDGES 200000
#define N_GRAPHS 4096
#define NODE_DIM 64
#define HID 256
#define N_GAT 4
#define NEG_SLOPE 0.2f
#define EPS 1e-9f
#define NB 98  // ceil(N_NODES/1024)

typedef const __attribute__((address_space(1))) void gv_t;
typedef __attribute__((address_space(3))) void lv_t;
typedef __attribute__((ext_vector_type(8))) short bf16x8;
typedef __attribute__((ext_vector_type(4))) float f32x4;

__device__ __forceinline__ float b2f(unsigned short u) {
    return __uint_as_float(((unsigned)u) << 16);
}
__device__ __forceinline__ unsigned short f2b(float f) {   // RNE
    unsigned u = __float_as_uint(f);
    return (unsigned short)((u + 0x7fffu + ((u >> 16) & 1u)) >> 16);
}

// ==================== converters ====================
__global__ void convert_f32_bf16(const float* __restrict__ src,
                                 unsigned short* __restrict__ dst, int n4) {
    int i = blockIdx.x * 256 + threadIdx.x;
    if (i >= n4) return;
    float4 v = ((const float4*)src)[i];
    ushort4 o;
    o.x = f2b(v.x); o.y = f2b(v.y); o.z = f2b(v.z); o.w = f2b(v.w);
    ((ushort4*)dst)[i] = o;
}

// Wt[c][k] = bf16(W[k][c]);  W is [K][256], Wt is [256][K].  blockIdx.z = layer.
__global__ __launch_bounds__(256) void transpose_bf16(const float* __restrict__ W0,
                                                      unsigned short* __restrict__ Wt0,
                                                      int K) {
    const float* W = W0 + (size_t)blockIdx.z * K * HID;
    unsigned short* Wt = Wt0 + (size_t)blockIdx.z * K * HID;
    __shared__ float tile[32][33];
    const int kb = blockIdx.x * 32, cb = blockIdx.y * 32;
    const int tr = threadIdx.x >> 5, tc = threadIdx.x & 31;
#pragma unroll
    for (int i = 0; i < 4; ++i)
        tile[tr + i * 8][tc] = W[(size_t)(kb + tr + i * 8) * HID + cb + tc];
    __syncthreads();
#pragma unroll
    for (int i = 0; i < 4; ++i)
        Wt[(size_t)(cb + tr + i * 8) * K + kb + tc] = f2b(tile[tc][tr + i * 8]);
}

// wal[l][k] = sum_c Wt[l][c][k]*al[l][c]  (el = z@al = h@(W@al)); same for war.
__global__ __launch_bounds__(256) void precompute_av(const unsigned short* __restrict__ Wt4,
                                                     const float* __restrict__ gal,
                                                     const float* __restrict__ gar,
                                                     float* __restrict__ wal,
                                                     float* __restrict__ war) {
    const int l = blockIdx.x, k = threadIdx.x;
    const unsigned short* Wt = Wt4 + (size_t)l * HID * HID;
    const float* al = gal + l * HID;
    const float* ar = gar + l * HID;
    float a = 0.f, b = 0.f;
    for (int c = 0; c < HID; ++c) {
        float w = b2f(Wt[(size_t)c * HID + k]);
        a = fmaf(w, al[c], a);
        b = fmaf(w, ar[c], b);
    }
    wal[l * HID + k] = a;
    war[l * HID + k] = b;
}

// ==================== MFMA GEMM ====================
// Y[M,256] = X[M,K](bf16) @ Wt[256,K](bf16, pre-transposed) (+bias).
// 128x128 block tile, 4 waves (64x64 each), 4x4 frags of 16x16x32 bf16 MFMA.
// 1D grid (ntiles*2), bijective XCD swizzle, col-half = fast bit (L2 X-reuse).
// Double-buffered LDS, stage(t+1) before compute(t).
// Epilogue: acc -> swizzled LDS bf16 tile (reuses xs) -> coalesced 16B stores.
template <int K, bool BIAS>
__global__ __launch_bounds__(256) void gemm_mfma(const unsigned short* __restrict__ Xb,
                                                 const unsigned short* __restrict__ Wt,
                                                 const float* __restrict__ bias,
                                                 unsigned short* __restrict__ Yb,
                                                 int M) {
    constexpr int KC = 64;
    constexpr int NT = K / KC;
    __shared__ unsigned short xs[2][128 * KC];   // staging + epilogue scratch (32KB)
    __shared__ unsigned short wsx[2][128 * KC];
    const int t = threadIdx.x, wv = t >> 6, ln = t & 63;
    const int wr2 = wv >> 1, wc2 = wv & 1;       // wave quadrant (2x2)

    // bijective XCD swizzle of flattened block id (m204 formula)
    const int nwg = gridDim.x;
    const int q8 = nwg >> 3, r8 = nwg & 7;
    const int xcd = blockIdx.x & 7, idx = blockIdx.x >> 3;
    const int sw = (xcd < r8) ? xcd * (q8 + 1) + idx : r8 * (q8 + 1) + (xcd - r8) * q8 + idx;
    const long row0 = (long)(sw >> 1) * 128;
    const int  col0 = (sw & 1) * 128;

    auto stage = [&](int buf, int k0) {
#pragma unroll
        for (int i = 0; i < 4; ++i) {
            const int chunk = wv * 4 + i;
            const int row = chunk * 8 + (ln >> 3);
            const int gsrc = (ln & 7) ^ (row & 7);
            long gr = row0 + row; if (gr >= M) gr = M - 1;
            const unsigned short* gp = Xb + gr * K + k0 + gsrc * 8;
            __builtin_amdgcn_global_load_lds((gv_t*)gp, (lv_t*)(&xs[buf][chunk * 512 + ln * 8]), 16, 0, 0);
        }
#pragma unroll
        for (int i = 0; i < 4; ++i) {
            const int chunk = wv * 4 + i;
            const int row = chunk * 8 + (ln >> 3);
            const int gsrc = (ln & 7) ^ (row & 7);
            const unsigned short* gp = Wt + (size_t)(col0 + row) * K + k0 + gsrc * 8;
            __builtin_amdgcn_global_load_lds((gv_t*)gp, (lv_t*)(&wsx[buf][chunk * 512 + ln * 8]), 16, 0, 0);
        }
    };

    f32x4 acc[4][4];
#pragma unroll
    for (int m = 0; m < 4; ++m)
#pragma unroll
        for (int n = 0; n < 4; ++n) acc[m][n] = (f32x4){0.f, 0.f, 0.f, 0.f};

    stage(0, 0);
    __syncthreads();

#pragma unroll
    for (int tt = 0; tt < NT; ++tt) {
        const int cur = tt & 1;
        if (tt + 1 < NT) stage(cur ^ 1, (tt + 1) * KC);   // prefetch overlaps compute

#pragma unroll
        for (int kk = 0; kk < 2; ++kk) {
            bf16x8 a[4], b[4];
            const int g = kk * 4 + (ln >> 4);
#pragma unroll
            for (int m = 0; m < 4; ++m) {
                const int row = wr2 * 64 + m * 16 + (ln & 15);
                const int s = g ^ (row & 7);
                a[m] = *(const bf16x8*)&xs[cur][row * 64 + s * 8];
            }
#pragma unroll
            for (int n = 0; n < 4; ++n) {
                const int row = wc2 * 64 + n * 16 + (ln & 15);
                const int s = g ^ (row & 7);
                b[n] = *(const bf16x8*)&wsx[cur][row * 64 + s * 8];
            }
#pragma unroll
            for (int m = 0; m < 4; ++m)
#pragma unroll
                for (int n = 0; n < 4; ++n)
                    acc[m][n] = __builtin_amdgcn_mfma_f32_16x16x32_bf16(a[m], b[n], acc[m][n], 0, 0, 0);
        }
        __syncthreads();   // drains prefetch + protects buffer reuse
    }

    // ---- epilogue: acc -> LDS bf16 tile (bank-swizzled) -> coalesced stores ----
    float bj[4];
#pragma unroll
    for (int n = 0; n < 4; ++n)
        bj[n] = BIAS ? bias[col0 + wc2 * 64 + n * 16 + (ln & 15)] : 0.f;

    char* ep = (char*)&xs[0][0];   // 32KB = full 128x128 bf16 tile
#pragma unroll
    for (int m = 0; m < 4; ++m) {
        const int rb = wr2 * 64 + m * 16 + 4 * (ln >> 4);
#pragma unroll
        for (int n = 0; n < 4; ++n) {
            const int colB = (wc2 * 64 + n * 16 + (ln & 15)) * 2;
#pragma unroll
            for (int qq = 0; qq < 4; ++qq) {
                const int rr = rb + qq;
                *(unsigned short*)(ep + rr * 256 + (colB ^ ((rr & 7) << 4))) = f2b(acc[m][n][qq] + bj[n]);
            }
        }
    }
    __syncthreads();
#pragma unroll
    for (int j = 0; j < 8; ++j) {
        const int row = t >> 1;
        const int cb = (t & 1) * 128 + j * 16;               // col byte within row
        uint4 v = *(const uint4*)(ep + row * 256 + (cb ^ ((row & 7) << 4)));
        const long r = row0 + row;
        if (r < M) *(uint4*)(Yb + r * HID + col0 + (cb >> 1)) = v;
    }
}

// ======================= CSR build (per launch) =======================
__global__ void hist_dst(const int* __restrict__ dst, int* __restrict__ deg) {
    int i = blockIdx.x * 256 + threadIdx.x;
    if (i < N_EDGES) atomicAdd(&deg[dst[i]], 1);
}

__global__ __launch_bounds__(1024) void scan_block(const int* __restrict__ deg,
                                                   int* __restrict__ sexc,
                                                   int* __restrict__ bsum) {
    int t = threadIdx.x, gid = blockIdx.x * 1024 + t;
    int v = (gid < N_NODES) ? deg[gid] : 0;
    int lane = t & 63, wv = t >> 6;
    int x = v;
#pragma unroll
    for (int o = 1; o < 64; o <<= 1) {
        int y = __shfl_up(x, o);
        if (lane >= o) x += y;
    }
    __shared__ int wsum[16];
    if (lane == 63) wsum[wv] = x;
    __syncthreads();
    if (t == 0) {
        int a = 0;
#pragma unroll
        for (int i = 0; i < 16; ++i) { int tt = wsum[i]; wsum[i] = a; a += tt; }
        bsum[blockIdx.x] = a;
    }
    __syncthreads();
    sexc[gid] = (x - v) + wsum[wv];
}

__global__ __launch_bounds__(128) void scan_partials(int* __restrict__ bsum,
                                                     int* __restrict__ offsets) {
    __shared__ int s[128];
    int t = threadIdx.x;
    int v = (t < NB) ? bsum[t] : 0;
    s[t] = v;
    __syncthreads();
    for (int o = 1; o < 128; o <<= 1) {
        int y = (t >= o) ? s[t - o] : 0;
        __syncthreads();
        s[t] += y;
        __syncthreads();
    }
    if (t < NB) bsum[t] = s[t] - v;
    if (t == 127) offsets[N_NODES] = s[127];
}

// writes offsets AND initializes cnt (= next free slot) in one pass
__global__ __launch_bounds__(1024) void scan_add(const int* __restrict__ sexc,
                                                 const int* __restrict__ bsum,
                                                 int* __restrict__ offsets,
                                                 int* __restrict__ cnt) {
    int gid = blockIdx.x * 1024 + threadIdx.x;
    if (gid < N_NODES) {
        int v = sexc[gid] + bsum[blockIdx.x];
        offsets[gid] = v;
        cnt[gid] = v;
    }
}

__global__ void csr_fill(const int* __restrict__ src, const int* __restrict__ dst,
                         int* __restrict__ cnt, int* __restrict__ csrc) {
    int i = blockIdx.x * 256 + threadIdx.x;
    if (i < N_EDGES) {
        int slot = atomicAdd(&cnt[dst[i]], 1);
        csrc[slot] = src[i];
    }
}

// goff[g] = lower_bound(graph_ids, g); graph_ids is sorted.
__global__ void graph_offsets(const int* __restrict__ gid, int* __restrict__ goff) {
    int g = blockIdx.x * 256 + threadIdx.x;
    if (g > N_GRAPHS) return;
    int lo = 0, hi = N_NODES;
    while (lo < hi) {
        int mid = (lo + hi) >> 1;
        if (gid[mid] < g) lo = mid + 1; else hi = mid;
    }
    goff[g] = lo;
}

// ===================== per-layer small kernels =====================
// el[n] = h[n]·wal, er[n] = h[n]·war for bf16 h. One wave per node.
__global__ void node_dots_b(const unsigned short* __restrict__ h,
                            const float* __restrict__ wal,
                            const float* __restrict__ war,
                            float* __restrict__ el, float* __restrict__ er) {
    int n = blockIdx.x * 4 + (threadIdx.x >> 6);
    int lane = threadIdx.x & 63;
    ushort4 zz = ((const ushort4*)(h + (size_t)n * HID))[lane];
    float4 a = ((const float4*)wal)[lane];
    float4 b = ((const float4*)war)[lane];
    float pl = b2f(zz.x) * a.x + b2f(zz.y) * a.y + b2f(zz.z) * a.z + b2f(zz.w) * a.w;
    float pr = b2f(zz.x) * b.x + b2f(zz.y) * b.y + b2f(zz.z) * b.z + b2f(zz.w) * b.w;
#pragma unroll
    for (int off = 32; off > 0; off >>= 1) {
        pl += __shfl_down(pl, off);
        pr += __shfl_down(pr, off);
    }
    if (lane == 0) { el[n] = pl; er[n] = pr; }
}

// One THREAD per node: segment softmax over its CSR edges -> alpha[c].
__global__ __launch_bounds__(256) void alpha_kernel(const int* __restrict__ offs,
                                                    const int* __restrict__ csrc,
                                                    const float* __restrict__ el,
                                                    const float* __restrict__ er,
                                                    float* __restrict__ alpha) {
    int n = blockIdx.x * 256 + threadIdx.x;
    if (n >= N_NODES) return;
    const int beg = offs[n], end = offs[n + 1];
    if (beg == end) return;
    const float ern = er[n];
    float m = -3.4e38f;
    for (int c = beg; c < end; ++c) {
        float v = el[csrc[c]] + ern;
        v = (v >= 0.f) ? v : NEG_SLOPE * v;
        alpha[c] = v;                      // stash e
        m = fmaxf(m, v);
    }
    float s = 0.f;
    for (int c = beg; c < end; ++c) {
        float a = __expf(alpha[c] - m);
        alpha[c] = a;
        s += a;
    }
    const float inv = 1.f / (s + EPS);
    for (int c = beg; c < end; ++c) alpha[c] *= inv;
}

// One wave per dst node: weighted gather + residual + ReLU; optionally also
// computes NEXT layer's el/er from the fresh f32 h (wal_next != nullptr).
__global__ __launch_bounds__(256) void gather_attn(const int* __restrict__ offs,
                                                   const int* __restrict__ csrc,
                                                   const float* __restrict__ alpha,
                                                   const unsigned short* __restrict__ z,
                                                   unsigned short* __restrict__ Ab,
                                                   const float* __restrict__ waln,
                                                   const float* __restrict__ warn,
                                                   float* __restrict__ el,
                                                   float* __restrict__ er) {
    const int n = blockIdx.x * 4 + (threadIdx.x >> 6);
    const int lane = threadIdx.x & 63;
    const int beg = offs[n], end = offs[n + 1];

    float4 acc = make_float4(0.f, 0.f, 0.f, 0.f);
    int c = beg;
    for (; c + 1 < end; c += 2) {
        float a0 = alpha[c], a1 = alpha[c + 1];
        int s0 = csrc[c], s1 = csrc[c + 1];
        ushort4 z0 = ((const ushort4*)(z + (size_t)s0 * HID))[lane];
        ushort4 z1 = ((const ushort4*)(z + (size_t)s1 * HID))[lane];
        acc.x = fmaf(a0, b2f(z0.x), acc.x); acc.x = fmaf(a1, b2f(z1.x), acc.x);
        acc.y = fmaf(a0, b2f(z0.y), acc.y); acc.y = fmaf(a1, b2f(z1.y), acc.y);
        acc.z = fmaf(a0, b2f(z0.z), acc.z); acc.z = fmaf(a1, b2f(z1.z), acc.z);
        acc.w = fmaf(a0, b2f(z0.w), acc.w); acc.w = fmaf(a1, b2f(z1.w), acc.w);
    }
    if (c < end) {
        float a = alpha[c];
        int sc = csrc[c];
        ushort4 zz = ((const ushort4*)(z + (size_t)sc * HID))[lane];
        acc.x = fmaf(a, b2f(zz.x), acc.x);
        acc.y = fmaf(a, b2f(zz.y), acc.y);
        acc.z = fmaf(a, b2f(zz.z), acc.z);
        acc.w = fmaf(a, b2f(zz.w), acc.w);
    }

    ushort4* Ap = (ushort4*)(Ab + (size_t)n * HID);
    ushort4 hh = Ap[lane];
    float h0 = fmaxf(b2f(hh.x) + acc.x, 0.f);
    float h1 = fmaxf(b2f(hh.y) + acc.y, 0.f);
    float h2 = fmaxf(b2f(hh.z) + acc.z, 0.f);
    float h3 = fmaxf(b2f(hh.w) + acc.w, 0.f);
    ushort4 ob;
    ob.x = f2b(h0); ob.y = f2b(h1); ob.z = f2b(h2); ob.w = f2b(h3);
    Ap[lane] = ob;

    if (waln) {   // wave-uniform branch: next layer's attention dots
        float4 wa = ((const float4*)waln)[lane];
        float4 wb = ((const float4*)warn)[lane];
        float pl = h0 * wa.x + h1 * wa.y + h2 * wa.z + h3 * wa.w;
        float pr = h0 * wb.x + h1 * wb.y + h2 * wb.z + h3 * wb.w;
#pragma unroll
        for (int o = 32; o > 0; o >>= 1) {
            pl += __shfl_down(pl, o);
            pr += __shfl_down(pr, o);
        }
        if (lane == 0) { el[n] = pl; er[n] = pr; }
    }
}

// g[gi,:] = sum of bf16 h rows in [goff[gi], goff[gi+1]) — sorted, no atomics
__global__ __launch_bounds__(256) void pool_seg(const unsigned short* __restrict__ h,
                                                const int* __restrict__ goff,
                                                float* __restrict__ g) {
    const int gi = blockIdx.x, t = threadIdx.x;
    const int beg = goff[gi], end = goff[gi + 1];
    float acc = 0.f;
    for (int n = beg; n < end; ++n) acc += b2f(h[(size_t)n * HID + t]);
    g[(size_t)gi * HID + t] = acc;
}

// fused MLP: relu(g@w1+b1) -> relu(@w2+b2) -> @w3+b3
__global__ void mlp_kernel(const float* __restrict__ g,
                           const float* __restrict__ w1, const float* __restrict__ b1,
                           const float* __restrict__ w2, const float* __restrict__ b2,
                           const float* __restrict__ w3, const float* __restrict__ b3,
                           float* __restrict__ out) {
    int gi = blockIdx.x, t = threadIdx.x;
    __shared__ float x[HID];
    __shared__ float y1[HID / 2];
    __shared__ float y2[HID / 4];
    x[t] = g[gi * HID + t];
    __syncthreads();
    if (t < HID / 2) {
        float a = b1[t];
#pragma unroll 8
        for (int k = 0; k < HID; ++k) a += x[k] * w1[k * (HID / 2) + t];
        y1[t] = fmaxf(a, 0.f);
    }
    __syncthreads();
    if (t < HID / 4) {
        float a = b2[t];
#pragma unroll 8
        for (int k = 0; k < HID / 2; ++k) a += y1[k] * w2[k * (HID / 4) + t];
        y2[t] = fmaxf(a, 0.f);
    }
    __syncthreads();
    if (t < 64) {
        float p = y2[t] * w3[t];
#pragma unroll
        for (int off = 32; off > 0; off >>= 1) p += __shfl_down(p, off);
        if (t == 0) out[gi] = p + b3[0];
    }
}

extern "C" void kernel_launch(void* const* d_in, const int* in_sizes, int n_in,
                              void* d_out, int out_size, void* d_ws, size_t ws_size,
                              hipStream_t stream) {
    const float* node_feats = (const float*)d_in[0];
    const int*   src        = (const int*)d_in[1];
    const int*   dst        = (const int*)d_in[2];
    const int*   graph_ids  = (const int*)d_in[3];
    const float* w_embed    = (const float*)d_in[4];
    const float* b_embed    = (const float*)d_in[5];
    const float* gat_W      = (const float*)d_in[6];
    const float* gat_al     = (const float*)d_in[7];
    const float* gat_ar     = (const float*)d_in[8];
    const float* w1         = (const float*)d_in[9];
    const float* b1         = (const float*)d_in[10];
    const float* w2         = (const float*)d_in[11];
    const float* b2         = (const float*)d_in[12];
    const float* w3         = (const float*)d_in[13];
    const float* b3         = (const float*)d_in[14];
    float* out = (float*)d_out;

    char* ws = (char*)d_ws;
    size_t off = 0;
    auto alloc = [&](size_t bytes) { char* p = ws + off; off += (bytes + 255) & ~size_t(255); return p; };
    unsigned short* Ab      = (unsigned short*)alloc((size_t)N_NODES * HID * 2); // h (bf16)
    unsigned short* Zb      = (unsigned short*)alloc((size_t)N_NODES * HID * 2); // z (bf16); aliases nfb
    unsigned short* Wte     = (unsigned short*)alloc((size_t)HID * NODE_DIM * 2);// embed W^T bf16
    unsigned short* Wtg     = (unsigned short*)alloc((size_t)N_GAT * HID * HID * 2); // GAT W^T bf16 (all layers)
    float*          wal     = (float*)alloc((size_t)N_GAT * HID * 4);            // W@al per layer
    float*          war     = (float*)alloc((size_t)N_GAT * HID * 4);            // W@ar per layer
    float*          eler    = (float*)alloc((size_t)2 * N_NODES * 4);            // el | er
    float*          alpha   = (float*)alloc((size_t)N_EDGES * 4);
    int*            deg     = (int*)alloc((size_t)N_NODES * 4);
    int*            cnt     = (int*)alloc((size_t)N_NODES * 4);
    int*            sexc    = (int*)alloc((size_t)NB * 1024 * 4);
    int*            bsum    = (int*)alloc(128 * 4);
    int*            offsets = (int*)alloc((size_t)(N_NODES + 1) * 4);
    int*            csrc    = (int*)alloc((size_t)N_EDGES * 4);
    int*            goff    = (int*)alloc((size_t)(N_GRAPHS + 1) * 4);
    float*          g       = (float*)alloc((size_t)N_GRAPHS * HID * 4);
    float*          el      = eler;
    float*          er      = eler + N_NODES;
    unsigned short* nfb     = Zb;  // node_feats bf16, dead before Zb first written

    // ---- CSR build + graph offsets (graph static across layers) ----
    hipMemsetAsync(deg, 0, (size_t)N_NODES * 4, stream);
    hist_dst<<<(N_EDGES + 255) / 256, 256, 0, stream>>>(dst, deg);
    scan_block<<<NB, 1024, 0, stream>>>(deg, sexc, bsum);
    scan_partials<<<1, 128, 0, stream>>>(bsum, offsets);
    scan_add<<<NB, 1024, 0, stream>>>(sexc, bsum, offsets, cnt);
    csr_fill<<<(N_EDGES + 255) / 256, 256, 0, stream>>>(src, dst, cnt, csrc);
    graph_offsets<<<(N_GRAPHS + 256) / 256, 256, 0, stream>>>(graph_ids, goff);

    // ---- all weight prep up front ----
    transpose_bf16<<<dim3(NODE_DIM / 32, HID / 32, 1), 256, 0, stream>>>(w_embed, Wte, NODE_DIM);
    transpose_bf16<<<dim3(HID / 32, HID / 32, N_GAT), 256, 0, stream>>>(gat_W, Wtg, HID);
    precompute_av<<<N_GAT, 256, 0, stream>>>(Wtg, gat_al, gat_ar, wal, war);
    convert_f32_bf16<<<(N_NODES * NODE_DIM / 4 + 255) / 256, 256, 0, stream>>>(node_feats, nfb, N_NODES * NODE_DIM / 4);

    const int ntm = (N_NODES + 127) / 128;       // 782 M-tiles
    const int ngrid = ntm * 2;                   // x2 column halves (1D, swizzled)

    // ---- embed: h = nf @ w_embed + b; then layer-0 el/er ----
    gemm_mfma<NODE_DIM, true><<<ngrid, 256, 0, stream>>>(nfb, Wte, b_embed, Ab, N_NODES);
    node_dots_b<<<N_NODES / 4, 256, 0, stream>>>(Ab, wal, war, el, er);

    for (int l = 0; l < N_GAT; ++l) {
        gemm_mfma<HID, false><<<ngrid, 256, 0, stream>>>(
            Ab, Wtg + (size_t)l * HID * HID, nullptr, Zb, N_NODES);
        alpha_kernel<<<(N_NODES + 255) / 256, 256, 0, stream>>>(offsets, csrc, el, er, alpha);
        const float* waln = (l < N_GAT - 1) ? wal + (l + 1) * HID : nullptr;
        const float* warn = (l < N_GAT - 1) ? war + (l + 1) * HID : nullptr;
        gather_attn<<<N_NODES / 4, 256, 0, stream>>>(offsets, csrc, alpha, Zb, Ab,
                                                     waln, warn, el, er);
    }

    pool_seg<<<N_GRAPHS, 256, 0, stream>>>(Ab, goff, g);
    mlp_kernel<<<N_GRAPHS, HID, 0, stream>>>(g, w1, b1, w2, b2, w3, b3, out);
}